// Round 1
// baseline (3643.478 us; speedup 1.0000x reference)
//
#include <hip/hip_runtime.h>
#include <hip/hip_bf16.h>

typedef unsigned short u16;
typedef unsigned int u32;
using short8 = __attribute__((ext_vector_type(8))) short;
using f32x4  = __attribute__((ext_vector_type(4))) float;

// ---------- helpers ----------
__device__ __forceinline__ u16 f2bu(float f) {            // f32 -> bf16 bits (RNE)
  u32 u = __builtin_bit_cast(u32, f);
  u32 r = u + 0x7fffu + ((u >> 16) & 1u);
  return (u16)(r >> 16);
}
__device__ __forceinline__ float bu2f(u16 u) {             // bf16 bits -> f32
  u32 x = ((u32)u) << 16;
  return __builtin_bit_cast(float, x);
}
__device__ __forceinline__ float waveRedSum(float v) {
  #pragma unroll
  for (int off = 32; off > 0; off >>= 1) v += __shfl_xor(v, off, 64);
  return v;
}
__device__ __forceinline__ void gload16(const void* g, void* l) {
  __builtin_amdgcn_global_load_lds((const __attribute__((address_space(1))) u32*)g,
                                   (__attribute__((address_space(3))) u32*)l, 16, 0, 0);
}

// ---------- GEMM: C[M,N] = A[M,K](bf16) * Bt[N,K](bf16)^T + bias, fused epilogues ----------
// MODE 0: C=f32 acc+bias | 1: Cb=bf16 relu(acc+bias) | 2: C += (acc+bias)*scale[row*4] | 3: C = (acc+bias)*scale[row*4]
template<int MODE>
__global__ __launch_bounds__(256) void gemm_bt(
    const u16* __restrict__ A, const u16* __restrict__ Bt,
    const float* __restrict__ bias,
    float* __restrict__ C, u16* __restrict__ Cb,
    const float* __restrict__ scale, int N, int K)
{
  __shared__ __align__(16) u16 As[128 * 32];
  __shared__ __align__(16) u16 Bs[128 * 32];
  const int tid = threadIdx.x;
  const int wave = tid >> 6, lane = tid & 63;
  const int wr = wave >> 1, wc = wave & 1;
  const int brow = blockIdx.y << 7, bcol = blockIdx.x << 7;
  const int r = lane & 15, kg = lane >> 4;

  f32x4 acc[4][4];
  #pragma unroll
  for (int m = 0; m < 4; ++m)
    #pragma unroll
    for (int n = 0; n < 4; ++n) acc[m][n] = f32x4{0.f, 0.f, 0.f, 0.f};

  const u16* Ab = A + (size_t)brow * K;
  const u16* Bb = Bt + (size_t)bcol * K;
  const int c0 = (wave << 6) + lane;             // chunk ids 0..255
  const int row0 = c0 >> 2, col0 = (c0 & 3) << 3;
  const int c1 = 256 + c0;                        // chunk ids 256..511
  const int row1 = c1 >> 2, col1 = (c1 & 3) << 3;

  for (int k0 = 0; k0 < K; k0 += 32) {
    __syncthreads();
    gload16(Ab + (size_t)row0 * K + k0 + col0, &As[(wave << 6) * 8]);
    gload16(Bb + (size_t)row0 * K + k0 + col0, &Bs[(wave << 6) * 8]);
    gload16(Ab + (size_t)row1 * K + k0 + col1, &As[(256 + (wave << 6)) * 8]);
    gload16(Bb + (size_t)row1 * K + k0 + col1, &Bs[(256 + (wave << 6)) * 8]);
    __syncthreads();
    short8 a[4], b[4];
    #pragma unroll
    for (int m = 0; m < 4; ++m)
      a[m] = *(const short8*)&As[((wr << 6) + (m << 4) + r) * 32 + (kg << 3)];
    #pragma unroll
    for (int n = 0; n < 4; ++n)
      b[n] = *(const short8*)&Bs[((wc << 6) + (n << 4) + r) * 32 + (kg << 3)];
    #pragma unroll
    for (int m = 0; m < 4; ++m)
      #pragma unroll
      for (int n = 0; n < 4; ++n)
        acc[m][n] = __builtin_amdgcn_mfma_f32_16x16x32_bf16(a[m], b[n], acc[m][n], 0, 0, 0);
  }

  #pragma unroll
  for (int m = 0; m < 4; ++m) {
    #pragma unroll
    for (int n = 0; n < 4; ++n) {
      const int col = bcol + (wc << 6) + (n << 4) + r;
      const float bv = bias[col];
      #pragma unroll
      for (int i = 0; i < 4; ++i) {
        const int row = brow + (wr << 6) + (m << 4) + (kg << 2) + i;
        float v = acc[m][n][i] + bv;
        const size_t off = (size_t)row * N + col;
        if constexpr (MODE == 0) C[off] = v;
        else if constexpr (MODE == 1) Cb[off] = f2bu(fmaxf(v, 0.f));
        else if constexpr (MODE == 2) C[off] += v * scale[(size_t)row << 2];
        else C[off] = v * scale[(size_t)row << 2];
      }
    }
  }
}

// ---------- transpose + convert: src f32 [K,N] -> dst bf16 [N,K]; grid.z batches ----------
__global__ __launch_bounds__(256) void tconv_kernel(const float* __restrict__ src, u16* __restrict__ dst,
                                                    int K, int N)
{
  __shared__ float t[32][33];
  const size_t moff = (size_t)blockIdx.z * K * N;
  const float* s = src + moff;
  u16* d = dst + moff;
  const int n0 = blockIdx.x << 5, k0 = blockIdx.y << 5;
  const int x = threadIdx.x, y = threadIdx.y;
  #pragma unroll
  for (int j = 0; j < 4; ++j) t[y + 8 * j][x] = s[(size_t)(k0 + y + 8 * j) * N + n0 + x];
  __syncthreads();
  #pragma unroll
  for (int j = 0; j < 4; ++j) d[(size_t)(n0 + y + 8 * j) * K + k0 + x] = f2bu(t[x][y + 8 * j]);
}

// ---------- f32 -> bf16 elementwise (4/thread, exact grid) ----------
__global__ __launch_bounds__(256) void conv_kernel(const float* __restrict__ in, u16* __restrict__ out)
{
  const size_t i = ((size_t)blockIdx.x * 256 + threadIdx.x) * 4;
  float4 v = *(const float4*)(in + i);
  *(ushort4*)(out + i) = make_ushort4(f2bu(v.x), f2bu(v.y), f2bu(v.z), f2bu(v.w));
}

// ---------- add sinusoidal positional encoding; write f32 + bf16 ----------
__global__ __launch_bounds__(256) void pe_kernel(float* __restrict__ X, u16* __restrict__ Xb)
{
  const int idx = blockIdx.x * 256 + threadIdx.x;
  const int d = idx & 1023;
  const int s = (idx >> 10) & 127;
  const float de = (float)(d & ~1);
  const float ang = (float)s * expf(de * (-9.210340371976184f / 1024.f));
  const float pe = (d & 1) ? cosf(ang) : sinf(ang);
  const float v = X[idx] + pe;
  X[idx] = v;
  Xb[idx] = f2bu(v);
}

// ---------- fused residual + layernorm; write f32 + bf16 ----------
__global__ __launch_bounds__(256) void ln_kernel(const float* __restrict__ Xi, const float* __restrict__ R,
    const float* __restrict__ g, const float* __restrict__ be,
    float* __restrict__ Xo, u16* __restrict__ Xbo)
{
  const size_t base = (size_t)blockIdx.x << 10;
  const int tid = threadIdx.x;
  float vals[4]; float s = 0.f, s2 = 0.f;
  #pragma unroll
  for (int j = 0; j < 4; ++j) {
    const int d = tid + (j << 8);
    const float v = Xi[base + d] + R[base + d];
    vals[j] = v; s += v; s2 += v * v;
  }
  s = waveRedSum(s); s2 = waveRedSum(s2);
  __shared__ float rs[4], rs2[4];
  const int wave = tid >> 6, lane = tid & 63;
  if (lane == 0) { rs[wave] = s; rs2[wave] = s2; }
  __syncthreads();
  s = rs[0] + rs[1] + rs[2] + rs[3];
  s2 = rs2[0] + rs2[1] + rs2[2] + rs2[3];
  const float mean = s * (1.f / 1024.f);
  const float var = s2 * (1.f / 1024.f) - mean * mean;
  const float inv = rsqrtf(var + 1e-5f);
  #pragma unroll
  for (int j = 0; j < 4; ++j) {
    const int d = tid + (j << 8);
    const float y = (vals[j] - mean) * inv * g[d] + be[d];
    Xo[base + d] = y;
    Xbo[base + d] = f2bu(y);
  }
}

// ---------- attention per (b,h): scores+softmax+PV; one block per head-batch ----------
__global__ __launch_bounds__(256) void attn_kernel(const float* __restrict__ QKV, u16* __restrict__ ATTb)
{
  __shared__ __align__(16) u16 Kb[128 * 128];
  __shared__ __align__(16) u16 Vb[128 * 128];
  __shared__ __align__(16) u16 Pb[128 * 128];
  __shared__ float red[256];
  const int b = blockIdx.x >> 3, h = blockIdx.x & 7;
  const int tid = threadIdx.x;
  const float* base = QKV + (size_t)b * 128 * 3072 + h * 128;

  for (int i = tid; i < 128 * 32; i += 256) {
    const int row = i >> 5, c4 = (i & 31) << 2;
    float4 kf = *(const float4*)(base + (size_t)row * 3072 + 1024 + c4);
    float4 vf = *(const float4*)(base + (size_t)row * 3072 + 2048 + c4);
    *(ushort4*)&Kb[row * 128 + c4] = make_ushort4(f2bu(kf.x), f2bu(kf.y), f2bu(kf.z), f2bu(kf.w));
    *(ushort4*)&Vb[row * 128 + c4] = make_ushort4(f2bu(vf.x), f2bu(vf.y), f2bu(vf.z), f2bu(vf.w));
  }
  __syncthreads();

  const int row = tid >> 1, half = tid & 1;
  const float* qrow = base + (size_t)row * 3072;
  float acc[64];
  #pragma unroll
  for (int c = 0; c < 64; ++c) acc[c] = 0.f;

  for (int d0 = 0; d0 < 128; d0 += 4) {
    float4 q = *(const float4*)(qrow + d0);
    #pragma unroll
    for (int c = 0; c < 64; ++c) {
      ushort4 k4 = *(const ushort4*)&Kb[(half * 64 + c) * 128 + d0];
      acc[c] += q.x * bu2f(k4.x) + q.y * bu2f(k4.y) + q.z * bu2f(k4.z) + q.w * bu2f(k4.w);
    }
  }

  const float sc = 0.08838834764831845f;  // 1/sqrt(128)
  float mx = -1e30f;
  #pragma unroll
  for (int c = 0; c < 64; ++c) { acc[c] *= sc; mx = fmaxf(mx, acc[c]); }
  red[tid] = mx;
  __syncthreads();
  mx = fmaxf(mx, red[tid ^ 1]);
  __syncthreads();
  float sum = 0.f;
  #pragma unroll
  for (int c = 0; c < 64; ++c) { float p = __expf(acc[c] - mx); acc[c] = p; sum += p; }
  red[tid] = sum;
  __syncthreads();
  sum += red[tid ^ 1];
  const float inv = 1.f / sum;
  #pragma unroll
  for (int c = 0; c < 64; c += 4)
    *(ushort4*)&Pb[row * 128 + half * 64 + c] = make_ushort4(
        f2bu(acc[c] * inv), f2bu(acc[c + 1] * inv), f2bu(acc[c + 2] * inv), f2bu(acc[c + 3] * inv));
  __syncthreads();

  float o[64];
  #pragma unroll
  for (int d = 0; d < 64; ++d) o[d] = 0.f;
  for (int c = 0; c < 128; ++c) {
    const float p = bu2f(Pb[row * 128 + c]);
    #pragma unroll
    for (int dq = 0; dq < 16; ++dq) {
      ushort4 v4 = *(const ushort4*)&Vb[c * 128 + half * 64 + (dq << 2)];
      o[dq * 4 + 0] += p * bu2f(v4.x);
      o[dq * 4 + 1] += p * bu2f(v4.y);
      o[dq * 4 + 2] += p * bu2f(v4.z);
      o[dq * 4 + 3] += p * bu2f(v4.w);
    }
  }
  u16* op = ATTb + (size_t)(b * 128 + row) * 1024 + h * 128 + half * 64;
  #pragma unroll
  for (int dq = 0; dq < 16; ++dq)
    *(ushort4*)(op + (dq << 2)) = make_ushort4(f2bu(o[dq * 4]), f2bu(o[dq * 4 + 1]),
                                               f2bu(o[dq * 4 + 2]), f2bu(o[dq * 4 + 3]));
}

// ---------- router: logits, top-2, softmax -> combine weights [N,4] ----------
__global__ __launch_bounds__(256) void router_kernel(const float* __restrict__ X, const float* __restrict__ rw,
    const float* __restrict__ rb, float* __restrict__ comb)
{
  const int token = blockIdx.x * 4 + (threadIdx.x >> 6);
  const int lane = threadIdx.x & 63;
  const float* xp = X + ((size_t)token << 10);
  float a0 = 0, a1 = 0, a2 = 0, a3 = 0;
  #pragma unroll
  for (int j = 0; j < 16; ++j) {
    const int k = lane + (j << 6);
    const float x = xp[k];
    const float4 w = *(const float4*)(rw + ((size_t)k << 2));
    a0 += x * w.x; a1 += x * w.y; a2 += x * w.z; a3 += x * w.w;
  }
  a0 = waveRedSum(a0); a1 = waveRedSum(a1); a2 = waveRedSum(a2); a3 = waveRedSum(a3);
  if (lane == 0) {
    float v[4] = {a0 + rb[0], a1 + rb[1], a2 + rb[2], a3 + rb[3]};
    int i1 = 0;
    for (int e = 1; e < 4; ++e) if (v[e] > v[i1]) i1 = e;       // earliest max (top_k tie rule)
    int i2 = (i1 == 0) ? 1 : 0;
    for (int e = 0; e < 4; ++e) if (e != i1 && v[e] > v[i2]) i2 = e;
    const float p2 = __expf(v[i2] - v[i1]);
    const float is = 1.f / (1.f + p2);
    float outv[4] = {0.f, 0.f, 0.f, 0.f};
    outv[i1] = is; outv[i2] = p2 * is;
    *(float4*)(comb + ((size_t)token << 2)) = make_float4(outv[0], outv[1], outv[2], outv[3]);
  }
}

// ---------- pooling score: s[token] = dot(x, attn_w) + attn_b ----------
__global__ __launch_bounds__(256) void score_kernel(const float* __restrict__ X, const float* __restrict__ aw,
    const float* __restrict__ ab, float* __restrict__ S)
{
  const int token = blockIdx.x * 4 + (threadIdx.x >> 6);
  const int lane = threadIdx.x & 63;
  const float* xp = X + ((size_t)token << 10);
  float s = 0.f;
  #pragma unroll
  for (int j = 0; j < 16; ++j) { const int k = lane + (j << 6); s += xp[k] * aw[k]; }
  s = waveRedSum(s);
  if (lane == 0) S[token] = s + ab[0];
}

// ---------- softmax over S per batch + weighted pool ----------
__global__ __launch_bounds__(256) void pool_kernel(const float* __restrict__ X, const float* __restrict__ S,
                                                   float* __restrict__ P)
{
  const int b = blockIdx.x;
  const int tid = threadIdx.x;
  __shared__ float p[128];
  if (tid < 128) p[tid] = S[b * 128 + tid];
  __syncthreads();
  float mx = -1e30f;
  for (int t = 0; t < 128; ++t) mx = fmaxf(mx, p[t]);
  float sum = 0.f;
  for (int t = 0; t < 128; ++t) sum += __expf(p[t] - mx);
  const float inv = 1.f / sum;
  __syncthreads();
  if (tid < 128) p[tid] = __expf(p[tid] - mx) * inv;
  __syncthreads();
  float acc[4] = {0.f, 0.f, 0.f, 0.f};
  for (int t = 0; t < 128; ++t) {
    const float pt = p[t];
    const float* xp = X + ((size_t)(b * 128 + t) << 10) + tid;
    #pragma unroll
    for (int j = 0; j < 4; ++j) acc[j] += pt * xp[j << 8];
  }
  #pragma unroll
  for (int j = 0; j < 4; ++j) P[((size_t)b << 10) + tid + (j << 8)] = acc[j];
}

// ---------- task heads: out[t,b,c] = dot(pooled[b], hw[t,:,c]) + hb[t,c] ----------
__global__ __launch_bounds__(256) void heads_kernel(const float* __restrict__ P, const float* __restrict__ hw,
    const float* __restrict__ hb, float* __restrict__ out)
{
  const int idx = blockIdx.x * 4 + (threadIdx.x >> 6);   // 0..1023 = t*256 + b*4 + c
  const int lane = threadIdx.x & 63;
  const int t = idx >> 8, b = (idx >> 2) & 63, c = idx & 3;
  const float* pp = P + ((size_t)b << 10);
  const float* wp = hw + (size_t)t * 4096 + c;
  float s = 0.f;
  #pragma unroll
  for (int j = 0; j < 16; ++j) { const int k = lane + (j << 6); s += pp[k] * wp[(size_t)k << 2]; }
  s = waveRedSum(s);
  if (lane == 0) out[idx] = s + hb[t * 4 + c];
}

// ---------- host ----------
extern "C" void kernel_launch(void* const* d_in, const int* in_sizes, int n_in,
                              void* d_out, int out_size, void* d_ws, size_t ws_size,
                              hipStream_t stream)
{
  (void)in_sizes; (void)n_in; (void)out_size; (void)ws_size;
  const float* vis        = (const float*)d_in[0];
  const float* proj_w     = (const float*)d_in[1];
  const float* proj_b     = (const float*)d_in[2];
  const float* in_proj_w  = (const float*)d_in[3];
  const float* in_proj_b  = (const float*)d_in[4];
  const float* out_proj_w = (const float*)d_in[5];
  const float* out_proj_b = (const float*)d_in[6];
  const float* ln1_g      = (const float*)d_in[7];
  const float* ln1_b      = (const float*)d_in[8];
  const float* ln2_g      = (const float*)d_in[9];
  const float* ln2_b      = (const float*)d_in[10];
  const float* router_w   = (const float*)d_in[11];
  const float* router_b   = (const float*)d_in[12];
  const float* ew1        = (const float*)d_in[13];
  const float* eb1        = (const float*)d_in[14];
  const float* ew2        = (const float*)d_in[15];
  const float* eb2        = (const float*)d_in[16];
  const float* attn_w     = (const float*)d_in[17];
  const float* attn_b     = (const float*)d_in[18];
  const float* heads_w    = (const float*)d_in[19];
  const float* heads_b    = (const float*)d_in[20];
  float* out = (float*)d_out;

  char* p = (char*)d_ws;
  auto take = [&](size_t bytes) -> char* {
    char* q = p; p += (bytes + 255) & ~(size_t)255; return q;
  };
  float* X    = (float*)take(8192ULL * 1024 * 4);
  u16*   Xb   = (u16*)  take(8192ULL * 1024 * 2);
  float* QKV  = (float*)take(8192ULL * 3072 * 4);
  u16*   ATTb = (u16*)  take(8192ULL * 1024 * 2);
  u16*   H    = (u16*)  take(8192ULL * 2048 * 2);
  float* COMB = (float*)take(8192ULL * 4 * 4);
  float* S    = (float*)take(8192ULL * 4);
  float* POOL = (float*)take(64ULL * 1024 * 4);
  u16*   Wqkv = (u16*)  take(3072ULL * 1024 * 2);
  u16*   Wout = (u16*)  take(1024ULL * 1024 * 2);
  u16*   We1  = (u16*)  take(4ULL * 2048 * 1024 * 2);
  u16*   We2  = (u16*)  take(4ULL * 1024 * 2048 * 2);
  // aliases into dead regions
  float* O     = QKV;                  // outproj result (QKV dead after attn)
  float* MOE   = QKV + 8192ULL * 1024; // moe accum     (disjoint from O)
  u16*   Wproj = We1;                  // used before layer 0 overwrites We1
  u16*   VISb  = H;                    // vis bf16 (25.2MB <= 33.5MB)

  const dim3 tb(32, 8);

  // projection: X = vis @ proj_w + proj_b
  tconv_kernel<<<dim3(1024 / 32, 1536 / 32, 1), tb, 0, stream>>>(proj_w, Wproj, 1536, 1024);
  conv_kernel<<<(8192 * 1536 / 4) / 256, 256, 0, stream>>>(vis, VISb);
  gemm_bt<0><<<dim3(8, 64), 256, 0, stream>>>(VISb, Wproj, proj_b, X, nullptr, nullptr, 1024, 1536);
  pe_kernel<<<8192 * 1024 / 256, 256, 0, stream>>>(X, Xb);

  for (int l = 0; l < 4; ++l) {
    tconv_kernel<<<dim3(3072 / 32, 1024 / 32, 1), tb, 0, stream>>>(in_proj_w + (size_t)l * 1024 * 3072, Wqkv, 1024, 3072);
    tconv_kernel<<<dim3(1024 / 32, 1024 / 32, 1), tb, 0, stream>>>(out_proj_w + (size_t)l * 1024 * 1024, Wout, 1024, 1024);
    tconv_kernel<<<dim3(2048 / 32, 1024 / 32, 4), tb, 0, stream>>>(ew1 + (size_t)l * 4 * 1024 * 2048, We1, 1024, 2048);
    tconv_kernel<<<dim3(1024 / 32, 2048 / 32, 4), tb, 0, stream>>>(ew2 + (size_t)l * 4 * 2048 * 1024, We2, 2048, 1024);

    gemm_bt<0><<<dim3(24, 64), 256, 0, stream>>>(Xb, Wqkv, in_proj_b + l * 3072, QKV, nullptr, nullptr, 3072, 1024);
    attn_kernel<<<512, 256, 0, stream>>>(QKV, ATTb);
    gemm_bt<0><<<dim3(8, 64), 256, 0, stream>>>(ATTb, Wout, out_proj_b + l * 1024, O, nullptr, nullptr, 1024, 1024);
    ln_kernel<<<8192, 256, 0, stream>>>(X, O, ln1_g + l * 1024, ln1_b + l * 1024, X, Xb);

    router_kernel<<<2048, 256, 0, stream>>>(X, router_w + l * 4096, router_b + l * 4, COMB);
    for (int e = 0; e < 4; ++e) {
      gemm_bt<1><<<dim3(16, 64), 256, 0, stream>>>(Xb, We1 + (size_t)e * 2048 * 1024,
          eb1 + (size_t)(l * 4 + e) * 2048, nullptr, H, nullptr, 2048, 1024);
      if (e == 0)
        gemm_bt<3><<<dim3(8, 64), 256, 0, stream>>>(H, We2 + (size_t)e * 1024 * 2048,
            eb2 + (size_t)(l * 4 + e) * 1024, MOE, nullptr, COMB + e, 1024, 2048);
      else
        gemm_bt<2><<<dim3(8, 64), 256, 0, stream>>>(H, We2 + (size_t)e * 1024 * 2048,
            eb2 + (size_t)(l * 4 + e) * 1024, MOE, nullptr, COMB + e, 1024, 2048);
    }
    ln_kernel<<<8192, 256, 0, stream>>>(X, MOE, ln2_g + l * 1024, ln2_b + l * 1024, X, Xb);
  }

  score_kernel<<<2048, 256, 0, stream>>>(X, attn_w, attn_b, S);
  pool_kernel<<<64, 256, 0, stream>>>(X, S, POOL);
  heads_kernel<<<256, 256, 0, stream>>>(POOL, heads_w, heads_b, out);
}

// Round 2
// 2966.434 us; speedup vs baseline: 1.2282x; 1.2282x over previous
//
#include <hip/hip_runtime.h>
#include <hip/hip_bf16.h>

typedef unsigned short u16;
typedef unsigned int u32;
using short8 = __attribute__((ext_vector_type(8))) short;
using f32x4  = __attribute__((ext_vector_type(4))) float;

// ---------- helpers ----------
__device__ __forceinline__ u16 f2bu(float f) {            // f32 -> bf16 bits (RNE)
  u32 u = __builtin_bit_cast(u32, f);
  u32 r = u + 0x7fffu + ((u >> 16) & 1u);
  return (u16)(r >> 16);
}
__device__ __forceinline__ float bu2f(u16 u) {             // bf16 bits -> f32
  u32 x = ((u32)u) << 16;
  return __builtin_bit_cast(float, x);
}
__device__ __forceinline__ float waveRedSum(float v) {
  #pragma unroll
  for (int off = 32; off > 0; off >>= 1) v += __shfl_xor(v, off, 64);
  return v;
}
__device__ __forceinline__ void gload16(const void* g, void* l) {
  __builtin_amdgcn_global_load_lds((const __attribute__((address_space(1))) u32*)g,
                                   (__attribute__((address_space(3))) u32*)l, 16, 0, 0);
}

// ---------- GEMM: C[M,N] = A[M,K](bf16) * Bt[N,K](bf16)^T + bias, fused epilogues ----------
// MODE 0: C=f32 acc+bias | 1: Cb=bf16 relu(acc+bias) | 2: C += (acc+bias)*scale[row*4] | 3: C = (acc+bias)*scale[row*4]
template<int MODE>
__global__ __launch_bounds__(256) void gemm_bt(
    const u16* __restrict__ A, const u16* __restrict__ Bt,
    const float* __restrict__ bias,
    float* __restrict__ C, u16* __restrict__ Cb,
    const float* __restrict__ scale, int N, int K)
{
  __shared__ __align__(16) u16 As[128 * 32];
  __shared__ __align__(16) u16 Bs[128 * 32];
  const int tid = threadIdx.x;
  const int wave = tid >> 6, lane = tid & 63;
  const int wr = wave >> 1, wc = wave & 1;
  const int brow = blockIdx.y << 7, bcol = blockIdx.x << 7;
  const int r = lane & 15, kg = lane >> 4;

  f32x4 acc[4][4];
  #pragma unroll
  for (int m = 0; m < 4; ++m)
    #pragma unroll
    for (int n = 0; n < 4; ++n) acc[m][n] = f32x4{0.f, 0.f, 0.f, 0.f};

  const u16* Ab = A + (size_t)brow * K;
  const u16* Bb = Bt + (size_t)bcol * K;
  const int c0 = (wave << 6) + lane;             // chunk ids 0..255
  const int row0 = c0 >> 2, col0 = (c0 & 3) << 3;
  const int c1 = 256 + c0;                        // chunk ids 256..511
  const int row1 = c1 >> 2, col1 = (c1 & 3) << 3;

  for (int k0 = 0; k0 < K; k0 += 32) {
    __syncthreads();
    gload16(Ab + (size_t)row0 * K + k0 + col0, &As[(wave << 6) * 8]);
    gload16(Bb + (size_t)row0 * K + k0 + col0, &Bs[(wave << 6) * 8]);
    gload16(Ab + (size_t)row1 * K + k0 + col1, &As[(256 + (wave << 6)) * 8]);
    gload16(Bb + (size_t)row1 * K + k0 + col1, &Bs[(256 + (wave << 6)) * 8]);
    __syncthreads();
    short8 a[4], b[4];
    #pragma unroll
    for (int m = 0; m < 4; ++m)
      a[m] = *(const short8*)&As[((wr << 6) + (m << 4) + r) * 32 + (kg << 3)];
    #pragma unroll
    for (int n = 0; n < 4; ++n)
      b[n] = *(const short8*)&Bs[((wc << 6) + (n << 4) + r) * 32 + (kg << 3)];
    #pragma unroll
    for (int m = 0; m < 4; ++m)
      #pragma unroll
      for (int n = 0; n < 4; ++n)
        acc[m][n] = __builtin_amdgcn_mfma_f32_16x16x32_bf16(a[m], b[n], acc[m][n], 0, 0, 0);
  }

  #pragma unroll
  for (int m = 0; m < 4; ++m) {
    #pragma unroll
    for (int n = 0; n < 4; ++n) {
      const int col = bcol + (wc << 6) + (n << 4) + r;
      const float bv = bias[col];
      #pragma unroll
      for (int i = 0; i < 4; ++i) {
        const int row = brow + (wr << 6) + (m << 4) + (kg << 2) + i;
        float v = acc[m][n][i] + bv;
        const size_t off = (size_t)row * N + col;
        if constexpr (MODE == 0) C[off] = v;
        else if constexpr (MODE == 1) Cb[off] = f2bu(fmaxf(v, 0.f));
        else if constexpr (MODE == 2) C[off] += v * scale[(size_t)row << 2];
        else C[off] = v * scale[(size_t)row << 2];
      }
    }
  }
}

// ---------- transpose + convert: src f32 [K,N] -> dst bf16 [N,K]; grid.z batches ----------
__global__ __launch_bounds__(256) void tconv_kernel(const float* __restrict__ src, u16* __restrict__ dst,
                                                    int K, int N)
{
  __shared__ float t[32][33];
  const size_t moff = (size_t)blockIdx.z * K * N;
  const float* s = src + moff;
  u16* d = dst + moff;
  const int n0 = blockIdx.x << 5, k0 = blockIdx.y << 5;
  const int x = threadIdx.x, y = threadIdx.y;
  #pragma unroll
  for (int j = 0; j < 4; ++j) t[y + 8 * j][x] = s[(size_t)(k0 + y + 8 * j) * N + n0 + x];
  __syncthreads();
  #pragma unroll
  for (int j = 0; j < 4; ++j) d[(size_t)(n0 + y + 8 * j) * K + k0 + x] = f2bu(t[x][y + 8 * j]);
}

// ---------- f32 -> bf16 elementwise (4/thread, exact grid) ----------
__global__ __launch_bounds__(256) void conv_kernel(const float* __restrict__ in, u16* __restrict__ out)
{
  const size_t i = ((size_t)blockIdx.x * 256 + threadIdx.x) * 4;
  float4 v = *(const float4*)(in + i);
  *(ushort4*)(out + i) = make_ushort4(f2bu(v.x), f2bu(v.y), f2bu(v.z), f2bu(v.w));
}

// ---------- add sinusoidal positional encoding; write f32 + bf16 ----------
__global__ __launch_bounds__(256) void pe_kernel(float* __restrict__ X, u16* __restrict__ Xb)
{
  const int idx = blockIdx.x * 256 + threadIdx.x;
  const int d = idx & 1023;
  const int s = (idx >> 10) & 127;
  const float de = (float)(d & ~1);
  const float ang = (float)s * expf(de * (-9.210340371976184f / 1024.f));
  const float pe = (d & 1) ? cosf(ang) : sinf(ang);
  const float v = X[idx] + pe;
  X[idx] = v;
  Xb[idx] = f2bu(v);
}

// ---------- fused residual + layernorm; write f32 + bf16 ----------
__global__ __launch_bounds__(256) void ln_kernel(const float* __restrict__ Xi, const float* __restrict__ R,
    const float* __restrict__ g, const float* __restrict__ be,
    float* __restrict__ Xo, u16* __restrict__ Xbo)
{
  const size_t base = (size_t)blockIdx.x << 10;
  const int tid = threadIdx.x;
  float vals[4]; float s = 0.f, s2 = 0.f;
  #pragma unroll
  for (int j = 0; j < 4; ++j) {
    const int d = tid + (j << 8);
    const float v = Xi[base + d] + R[base + d];
    vals[j] = v; s += v; s2 += v * v;
  }
  s = waveRedSum(s); s2 = waveRedSum(s2);
  __shared__ float rs[4], rs2[4];
  const int wave = tid >> 6, lane = tid & 63;
  if (lane == 0) { rs[wave] = s; rs2[wave] = s2; }
  __syncthreads();
  s = rs[0] + rs[1] + rs[2] + rs[3];
  s2 = rs2[0] + rs2[1] + rs2[2] + rs2[3];
  const float mean = s * (1.f / 1024.f);
  const float var = s2 * (1.f / 1024.f) - mean * mean;
  const float inv = rsqrtf(var + 1e-5f);
  #pragma unroll
  for (int j = 0; j < 4; ++j) {
    const int d = tid + (j << 8);
    const float y = (vals[j] - mean) * inv * g[d] + be[d];
    Xo[base + d] = y;
    Xbo[base + d] = f2bu(y);
  }
}

// ---------- MFMA attention per (b,h): 4 waves, each owns 32 Q-rows ----------
// LDS rows padded to 136 elems (272B stride) -> frag reads are 2-way bank aliased (free).
#define LDW 136
__global__ __launch_bounds__(256) void attn_mfma_kernel(const float* __restrict__ QKV, u16* __restrict__ ATTb)
{
  __shared__ __align__(16) u16 Kb[128 * LDW];   // [key][d]
  __shared__ __align__(16) u16 Vt[128 * LDW];   // [d][key]
  __shared__ __align__(16) u16 Pb[128 * LDW];   // [q][key] (wave-private rows)
  const int b = blockIdx.x >> 3, h = blockIdx.x & 7;
  const int tid = threadIdx.x;
  const int wave = tid >> 6, lane = tid & 63;
  const int r = lane & 15, kg = lane >> 4;
  const float* base = QKV + (size_t)b * 128 * 3072 + h * 128;

  // stage K row-major
  for (int i = tid; i < 128 * 32; i += 256) {
    const int row = i >> 5, c4 = (i & 31) << 2;
    float4 kf = *(const float4*)(base + (size_t)row * 3072 + 1024 + c4);
    *(ushort4*)&Kb[row * LDW + c4] = make_ushort4(f2bu(kf.x), f2bu(kf.y), f2bu(kf.z), f2bu(kf.w));
  }
  // stage V transposed: lanes walk d (coalesced global read), scatter to Vt[d][key]
  for (int i = tid; i < 128 * 128; i += 256) {
    const int d = i & 127, key = i >> 7;
    Vt[d * LDW + key] = f2bu(base[(size_t)key * 3072 + 2048 + d]);
  }

  // Q fragments straight from global (rows wave*32 .. +32)
  short8 a[2][4];
  #pragma unroll
  for (int m = 0; m < 2; ++m) {
    const int row = wave * 32 + m * 16 + r;
    const float* qp = base + (size_t)row * 3072;
    #pragma unroll
    for (int ks = 0; ks < 4; ++ks) {
      float4 q0 = *(const float4*)(qp + ks * 32 + kg * 8);
      float4 q1 = *(const float4*)(qp + ks * 32 + kg * 8 + 4);
      short8 av;
      av[0] = f2bu(q0.x); av[1] = f2bu(q0.y); av[2] = f2bu(q0.z); av[3] = f2bu(q0.w);
      av[4] = f2bu(q1.x); av[5] = f2bu(q1.y); av[6] = f2bu(q1.z); av[7] = f2bu(q1.w);
      a[m][ks] = av;
    }
  }
  __syncthreads();

  // QK^T: acc[m][n] covers rows wave*32+m*16.., cols n*16..
  f32x4 acc[2][8];
  #pragma unroll
  for (int m = 0; m < 2; ++m)
    #pragma unroll
    for (int n = 0; n < 8; ++n) acc[m][n] = f32x4{0.f, 0.f, 0.f, 0.f};
  #pragma unroll
  for (int n = 0; n < 8; ++n) {
    #pragma unroll
    for (int ks = 0; ks < 4; ++ks) {
      short8 bf = *(const short8*)&Kb[(n * 16 + r) * LDW + ks * 32 + kg * 8];
      #pragma unroll
      for (int m = 0; m < 2; ++m)
        acc[m][n] = __builtin_amdgcn_mfma_f32_16x16x32_bf16(a[m][ks], bf, acc[m][n], 0, 0, 0);
    }
  }

  // row softmax: row = wave*32 + m*16 + kg*4 + i lives in lanes sharing kg; reduce over r
  const float sc = 0.08838834764831845f;  // 1/sqrt(128)
  #pragma unroll
  for (int m = 0; m < 2; ++m) {
    #pragma unroll
    for (int i = 0; i < 4; ++i) {
      float mx = -1e30f;
      #pragma unroll
      for (int n = 0; n < 8; ++n) mx = fmaxf(mx, acc[m][n][i]);
      #pragma unroll
      for (int msk = 1; msk < 16; msk <<= 1) mx = fmaxf(mx, __shfl_xor(mx, msk, 64));
      float s = 0.f;
      #pragma unroll
      for (int n = 0; n < 8; ++n) { float pv = __expf((acc[m][n][i] - mx) * sc); acc[m][n][i] = pv; s += pv; }
      #pragma unroll
      for (int msk = 1; msk < 16; msk <<= 1) s += __shfl_xor(s, msk, 64);
      const float inv = 1.f / s;
      #pragma unroll
      for (int n = 0; n < 8; ++n) {
        const int prow = wave * 32 + m * 16 + kg * 4 + i;
        Pb[prow * LDW + n * 16 + r] = f2bu(acc[m][n][i] * inv);
      }
    }
  }
  // Pb rows are wave-private: no barrier needed (within-wave LDS ordering via waitcnt)

  // PV: O[rows][d] = P x V; A-frags from Pb (own rows), B-frags from Vt
  f32x4 oacc[2][8];
  #pragma unroll
  for (int m = 0; m < 2; ++m)
    #pragma unroll
    for (int n = 0; n < 8; ++n) oacc[m][n] = f32x4{0.f, 0.f, 0.f, 0.f};
  #pragma unroll
  for (int ks = 0; ks < 4; ++ks) {
    short8 pa[2];
    #pragma unroll
    for (int m = 0; m < 2; ++m)
      pa[m] = *(const short8*)&Pb[(wave * 32 + m * 16 + r) * LDW + ks * 32 + kg * 8];
    #pragma unroll
    for (int n = 0; n < 8; ++n) {
      short8 vb = *(const short8*)&Vt[(n * 16 + r) * LDW + ks * 32 + kg * 8];
      #pragma unroll
      for (int m = 0; m < 2; ++m)
        oacc[m][n] = __builtin_amdgcn_mfma_f32_16x16x32_bf16(pa[m], vb, oacc[m][n], 0, 0, 0);
    }
  }

  // write O as bf16 to ATTb[b*128+row][h*128+col]
  u16* op = ATTb + ((size_t)b * 128) * 1024 + h * 128;
  #pragma unroll
  for (int m = 0; m < 2; ++m) {
    #pragma unroll
    for (int n = 0; n < 8; ++n) {
      #pragma unroll
      for (int i = 0; i < 4; ++i) {
        const int row = wave * 32 + m * 16 + kg * 4 + i;
        op[(size_t)row * 1024 + n * 16 + r] = f2bu(oacc[m][n][i]);
      }
    }
  }
}
#undef LDW

// ---------- router: logits, top-2, softmax -> combine weights [N,4] ----------
__global__ __launch_bounds__(256) void router_kernel(const float* __restrict__ X, const float* __restrict__ rw,
    const float* __restrict__ rb, float* __restrict__ comb)
{
  const int token = blockIdx.x * 4 + (threadIdx.x >> 6);
  const int lane = threadIdx.x & 63;
  const float* xp = X + ((size_t)token << 10);
  float a0 = 0, a1 = 0, a2 = 0, a3 = 0;
  #pragma unroll
  for (int j = 0; j < 16; ++j) {
    const int k = lane + (j << 6);
    const float x = xp[k];
    const float4 w = *(const float4*)(rw + ((size_t)k << 2));
    a0 += x * w.x; a1 += x * w.y; a2 += x * w.z; a3 += x * w.w;
  }
  a0 = waveRedSum(a0); a1 = waveRedSum(a1); a2 = waveRedSum(a2); a3 = waveRedSum(a3);
  if (lane == 0) {
    float v[4] = {a0 + rb[0], a1 + rb[1], a2 + rb[2], a3 + rb[3]};
    int i1 = 0;
    for (int e = 1; e < 4; ++e) if (v[e] > v[i1]) i1 = e;       // earliest max (top_k tie rule)
    int i2 = (i1 == 0) ? 1 : 0;
    for (int e = 0; e < 4; ++e) if (e != i1 && v[e] > v[i2]) i2 = e;
    const float p2 = __expf(v[i2] - v[i1]);
    const float is = 1.f / (1.f + p2);
    float outv[4] = {0.f, 0.f, 0.f, 0.f};
    outv[i1] = is; outv[i2] = p2 * is;
    *(float4*)(comb + ((size_t)token << 2)) = make_float4(outv[0], outv[1], outv[2], outv[3]);
  }
}

// ---------- pooling score: s[token] = dot(x, attn_w) + attn_b ----------
__global__ __launch_bounds__(256) void score_kernel(const float* __restrict__ X, const float* __restrict__ aw,
    const float* __restrict__ ab, float* __restrict__ S)
{
  const int token = blockIdx.x * 4 + (threadIdx.x >> 6);
  const int lane = threadIdx.x & 63;
  const float* xp = X + ((size_t)token << 10);
  float s = 0.f;
  #pragma unroll
  for (int j = 0; j < 16; ++j) { const int k = lane + (j << 6); s += xp[k] * aw[k]; }
  s = waveRedSum(s);
  if (lane == 0) S[token] = s + ab[0];
}

// ---------- softmax over S per batch + weighted pool ----------
__global__ __launch_bounds__(256) void pool_kernel(const float* __restrict__ X, const float* __restrict__ S,
                                                   float* __restrict__ P)
{
  const int b = blockIdx.x;
  const int tid = threadIdx.x;
  __shared__ float p[128];
  if (tid < 128) p[tid] = S[b * 128 + tid];
  __syncthreads();
  float mx = -1e30f;
  for (int t = 0; t < 128; ++t) mx = fmaxf(mx, p[t]);
  float sum = 0.f;
  for (int t = 0; t < 128; ++t) sum += __expf(p[t] - mx);
  const float inv = 1.f / sum;
  __syncthreads();
  if (tid < 128) p[tid] = __expf(p[tid] - mx) * inv;
  __syncthreads();
  float acc[4] = {0.f, 0.f, 0.f, 0.f};
  for (int t = 0; t < 128; ++t) {
    const float pt = p[t];
    const float* xp = X + ((size_t)(b * 128 + t) << 10) + tid;
    #pragma unroll
    for (int j = 0; j < 4; ++j) acc[j] += pt * xp[j << 8];
  }
  #pragma unroll
  for (int j = 0; j < 4; ++j) P[((size_t)b << 10) + tid + (j << 8)] = acc[j];
}

// ---------- task heads: out[t,b,c] = dot(pooled[b], hw[t,:,c]) + hb[t,c] ----------
__global__ __launch_bounds__(256) void heads_kernel(const float* __restrict__ P, const float* __restrict__ hw,
    const float* __restrict__ hb, float* __restrict__ out)
{
  const int idx = blockIdx.x * 4 + (threadIdx.x >> 6);   // 0..1023 = t*256 + b*4 + c
  const int lane = threadIdx.x & 63;
  const int t = idx >> 8, b = (idx >> 2) & 63, c = idx & 3;
  const float* pp = P + ((size_t)b << 10);
  const float* wp = hw + (size_t)t * 4096 + c;
  float s = 0.f;
  #pragma unroll
  for (int j = 0; j < 16; ++j) { const int k = lane + (j << 6); s += pp[k] * wp[(size_t)k << 2]; }
  s = waveRedSum(s);
  if (lane == 0) out[idx] = s + hb[t * 4 + c];
}

// ---------- host ----------
extern "C" void kernel_launch(void* const* d_in, const int* in_sizes, int n_in,
                              void* d_out, int out_size, void* d_ws, size_t ws_size,
                              hipStream_t stream)
{
  (void)in_sizes; (void)n_in; (void)out_size; (void)ws_size;
  const float* vis        = (const float*)d_in[0];
  const float* proj_w     = (const float*)d_in[1];
  const float* proj_b     = (const float*)d_in[2];
  const float* in_proj_w  = (const float*)d_in[3];
  const float* in_proj_b  = (const float*)d_in[4];
  const float* out_proj_w = (const float*)d_in[5];
  const float* out_proj_b = (const float*)d_in[6];
  const float* ln1_g      = (const float*)d_in[7];
  const float* ln1_b      = (const float*)d_in[8];
  const float* ln2_g      = (const float*)d_in[9];
  const float* ln2_b      = (const float*)d_in[10];
  const float* router_w   = (const float*)d_in[11];
  const float* router_b   = (const float*)d_in[12];
  const float* ew1        = (const float*)d_in[13];
  const float* eb1        = (const float*)d_in[14];
  const float* ew2        = (const float*)d_in[15];
  const float* eb2        = (const float*)d_in[16];
  const float* attn_w     = (const float*)d_in[17];
  const float* attn_b     = (const float*)d_in[18];
  const float* heads_w    = (const float*)d_in[19];
  const float* heads_b    = (const float*)d_in[20];
  float* out = (float*)d_out;

  char* p = (char*)d_ws;
  auto take = [&](size_t bytes) -> char* {
    char* q = p; p += (bytes + 255) & ~(size_t)255; return q;
  };
  float* X    = (float*)take(8192ULL * 1024 * 4);
  u16*   Xb   = (u16*)  take(8192ULL * 1024 * 2);
  float* QKV  = (float*)take(8192ULL * 3072 * 4);
  u16*   ATTb = (u16*)  take(8192ULL * 1024 * 2);
  u16*   H    = (u16*)  take(8192ULL * 2048 * 2);
  float* COMB = (float*)take(8192ULL * 4 * 4);
  float* S    = (float*)take(8192ULL * 4);
  float* POOL = (float*)take(64ULL * 1024 * 4);
  u16*   Wqkv = (u16*)  take(3072ULL * 1024 * 2);
  u16*   Wout = (u16*)  take(1024ULL * 1024 * 2);
  u16*   We1  = (u16*)  take(4ULL * 2048 * 1024 * 2);
  u16*   We2  = (u16*)  take(4ULL * 1024 * 2048 * 2);
  // aliases into dead regions
  float* O     = QKV;                  // outproj result (QKV dead after attn)
  float* MOE   = QKV + 8192ULL * 1024; // moe accum     (disjoint from O)
  u16*   Wproj = We1;                  // used before layer 0 overwrites We1
  u16*   VISb  = H;                    // vis bf16 (25.2MB <= 33.5MB)

  const dim3 tb(32, 8);

  // projection: X = vis @ proj_w + proj_b
  tconv_kernel<<<dim3(1024 / 32, 1536 / 32, 1), tb, 0, stream>>>(proj_w, Wproj, 1536, 1024);
  conv_kernel<<<(8192 * 1536 / 4) / 256, 256, 0, stream>>>(vis, VISb);
  gemm_bt<0><<<dim3(8, 64), 256, 0, stream>>>(VISb, Wproj, proj_b, X, nullptr, nullptr, 1024, 1536);
  pe_kernel<<<8192 * 1024 / 256, 256, 0, stream>>>(X, Xb);

  for (int l = 0; l < 4; ++l) {
    tconv_kernel<<<dim3(3072 / 32, 1024 / 32, 1), tb, 0, stream>>>(in_proj_w + (size_t)l * 1024 * 3072, Wqkv, 1024, 3072);
    tconv_kernel<<<dim3(1024 / 32, 1024 / 32, 1), tb, 0, stream>>>(out_proj_w + (size_t)l * 1024 * 1024, Wout, 1024, 1024);
    tconv_kernel<<<dim3(2048 / 32, 1024 / 32, 4), tb, 0, stream>>>(ew1 + (size_t)l * 4 * 1024 * 2048, We1, 1024, 2048);
    tconv_kernel<<<dim3(1024 / 32, 2048 / 32, 4), tb, 0, stream>>>(ew2 + (size_t)l * 4 * 2048 * 1024, We2, 2048, 1024);

    gemm_bt<0><<<dim3(24, 64), 256, 0, stream>>>(Xb, Wqkv, in_proj_b + l * 3072, QKV, nullptr, nullptr, 3072, 1024);
    attn_mfma_kernel<<<512, 256, 0, stream>>>(QKV, ATTb);
    gemm_bt<0><<<dim3(8, 64), 256, 0, stream>>>(ATTb, Wout, out_proj_b + l * 1024, O, nullptr, nullptr, 1024, 1024);
    ln_kernel<<<8192, 256, 0, stream>>>(X, O, ln1_g + l * 1024, ln1_b + l * 1024, X, Xb);

    router_kernel<<<2048, 256, 0, stream>>>(X, router_w + l * 4096, router_b + l * 4, COMB);
    for (int e = 0; e < 4; ++e) {
      gemm_bt<1><<<dim3(16, 64), 256, 0, stream>>>(Xb, We1 + (size_t)e * 2048 * 1024,
          eb1 + (size_t)(l * 4 + e) * 2048, nullptr, H, nullptr, 2048, 1024);
      if (e == 0)
        gemm_bt<3><<<dim3(8, 64), 256, 0, stream>>>(H, We2 + (size_t)e * 1024 * 2048,
            eb2 + (size_t)(l * 4 + e) * 1024, MOE, nullptr, COMB + e, 1024, 2048);
      else
        gemm_bt<2><<<dim3(8, 64), 256, 0, stream>>>(H, We2 + (size_t)e * 1024 * 2048,
            eb2 + (size_t)(l * 4 + e) * 1024, MOE, nullptr, COMB + e, 1024, 2048);
    }
    ln_kernel<<<8192, 256, 0, stream>>>(X, MOE, ln2_g + l * 1024, ln2_b + l * 1024, X, Xb);
  }

  score_kernel<<<2048, 256, 0, stream>>>(X, attn_w, attn_b, S);
  pool_kernel<<<64, 256, 0, stream>>>(X, S, POOL);
  heads_kernel<<<256, 256, 0, stream>>>(POOL, heads_w, heads_b, out);
}

// Round 3
// 2930.234 us; speedup vs baseline: 1.2434x; 1.0124x over previous
//
#include <hip/hip_runtime.h>
#include <hip/hip_bf16.h>

typedef unsigned short u16;
typedef unsigned int u32;
using short8 = __attribute__((ext_vector_type(8))) short;
using f32x4  = __attribute__((ext_vector_type(4))) float;

// ---------- helpers ----------
__device__ __forceinline__ u16 f2bu(float f) {            // f32 -> bf16 bits (RNE)
  u32 u = __builtin_bit_cast(u32, f);
  u32 r = u + 0x7fffu + ((u >> 16) & 1u);
  return (u16)(r >> 16);
}
__device__ __forceinline__ float bu2f(u16 u) {             // bf16 bits -> f32
  u32 x = ((u32)u) << 16;
  return __builtin_bit_cast(float, x);
}
__device__ __forceinline__ float waveRedSum(float v) {
  #pragma unroll
  for (int off = 32; off > 0; off >>= 1) v += __shfl_xor(v, off, 64);
  return v;
}
__device__ __forceinline__ void gload16(const void* g, void* l) {
  __builtin_amdgcn_global_load_lds((const __attribute__((address_space(1))) u32*)g,
                                   (__attribute__((address_space(3))) u32*)l, 16, 0, 0);
}

// ---------- GEMM: C[M,N] = A[M,K](bf16) * Bt[N,K](bf16)^T + bias ----------
// MODE 0: C f32 = acc+bias | MODE 2: Cb bf16 = acc+bias
template<int MODE>
__global__ __launch_bounds__(256) void gemm_bt(
    const u16* __restrict__ A, const u16* __restrict__ Bt,
    const float* __restrict__ bias,
    float* __restrict__ C, u16* __restrict__ Cb, int N, int K)
{
  __shared__ __align__(16) u16 As[128 * 32];
  __shared__ __align__(16) u16 Bs[128 * 32];
  const int tid = threadIdx.x;
  const int wave = tid >> 6, lane = tid & 63;
  const int wr = wave >> 1, wc = wave & 1;
  const int brow = blockIdx.y << 7, bcol = blockIdx.x << 7;
  const int r = lane & 15, kg = lane >> 4;

  f32x4 acc[4][4];
  #pragma unroll
  for (int m = 0; m < 4; ++m)
    #pragma unroll
    for (int n = 0; n < 4; ++n) acc[m][n] = f32x4{0.f, 0.f, 0.f, 0.f};

  const u16* Ab = A + (size_t)brow * K;
  const u16* Bb = Bt + (size_t)bcol * K;
  const int c0 = (wave << 6) + lane;
  const int row0 = c0 >> 2, col0 = (c0 & 3) << 3;
  const int c1 = 256 + c0;
  const int row1 = c1 >> 2, col1 = (c1 & 3) << 3;

  for (int k0 = 0; k0 < K; k0 += 32) {
    __syncthreads();
    gload16(Ab + (size_t)row0 * K + k0 + col0, &As[(wave << 6) * 8]);
    gload16(Bb + (size_t)row0 * K + k0 + col0, &Bs[(wave << 6) * 8]);
    gload16(Ab + (size_t)row1 * K + k0 + col1, &As[(256 + (wave << 6)) * 8]);
    gload16(Bb + (size_t)row1 * K + k0 + col1, &Bs[(256 + (wave << 6)) * 8]);
    __syncthreads();
    short8 a[4], b[4];
    #pragma unroll
    for (int m = 0; m < 4; ++m)
      a[m] = *(const short8*)&As[((wr << 6) + (m << 4) + r) * 32 + (kg << 3)];
    #pragma unroll
    for (int n = 0; n < 4; ++n)
      b[n] = *(const short8*)&Bs[((wc << 6) + (n << 4) + r) * 32 + (kg << 3)];
    #pragma unroll
    for (int m = 0; m < 4; ++m)
      #pragma unroll
      for (int n = 0; n < 4; ++n)
        acc[m][n] = __builtin_amdgcn_mfma_f32_16x16x32_bf16(a[m], b[n], acc[m][n], 0, 0, 0);
  }

  #pragma unroll
  for (int m = 0; m < 4; ++m) {
    #pragma unroll
    for (int n = 0; n < 4; ++n) {
      const int col = bcol + (wc << 6) + (n << 4) + r;
      const float bv = bias[col];
      #pragma unroll
      for (int i = 0; i < 4; ++i) {
        const int row = brow + (wr << 6) + (m << 4) + (kg << 2) + i;
        float v = acc[m][n][i] + bv;
        const size_t off = (size_t)row * N + col;
        if constexpr (MODE == 0) C[off] = v;
        else Cb[off] = f2bu(v);
      }
    }
  }
}

// ---------- MoE GEMM 1: gather rows of A by token list; H = relu(A[tok] @ W1^T + b1), bf16 compact ----------
__global__ __launch_bounds__(256) void gemm_moe1(
    const u16* __restrict__ A,        // Xb [8192][1024]
    const u16* __restrict__ Bt,       // We1_e [2048][1024]
    const float* __restrict__ bias,   // eb1_e [2048]
    u16* __restrict__ Hc,             // compact H [8192][2048]
    const int* __restrict__ tok, const int* __restrict__ cntPtr)
{
  const int cnt = *cntPtr;
  const int brow = blockIdx.y << 7;
  if (brow >= ((cnt + 127) & ~127)) return;
  const int K = 1024, N = 2048;
  __shared__ __align__(16) u16 As[128 * 32];
  __shared__ __align__(16) u16 Bs[128 * 32];
  const int tid = threadIdx.x;
  const int wave = tid >> 6, lane = tid & 63;
  const int wr = wave >> 1, wc = wave & 1;
  const int bcol = blockIdx.x << 7;
  const int r = lane & 15, kg = lane >> 4;

  f32x4 acc[4][4];
  #pragma unroll
  for (int m = 0; m < 4; ++m)
    #pragma unroll
    for (int n = 0; n < 4; ++n) acc[m][n] = f32x4{0.f, 0.f, 0.f, 0.f};

  const u16* Bb = Bt + (size_t)bcol * K;
  const int c0 = (wave << 6) + lane;
  const int row0 = c0 >> 2, col0 = (c0 & 3) << 3;
  const int c1 = 256 + c0;
  const int row1 = c1 >> 2, col1 = (c1 & 3) << 3;
  const int t0 = (brow + row0 < cnt) ? tok[brow + row0] : 0;
  const int t1 = (brow + row1 < cnt) ? tok[brow + row1] : 0;

  for (int k0 = 0; k0 < K; k0 += 32) {
    __syncthreads();
    gload16(A + (size_t)t0 * K + k0 + col0, &As[(wave << 6) * 8]);
    gload16(Bb + (size_t)row0 * K + k0 + col0, &Bs[(wave << 6) * 8]);
    gload16(A + (size_t)t1 * K + k0 + col1, &As[(256 + (wave << 6)) * 8]);
    gload16(Bb + (size_t)row1 * K + k0 + col1, &Bs[(256 + (wave << 6)) * 8]);
    __syncthreads();
    short8 a[4], b[4];
    #pragma unroll
    for (int m = 0; m < 4; ++m)
      a[m] = *(const short8*)&As[((wr << 6) + (m << 4) + r) * 32 + (kg << 3)];
    #pragma unroll
    for (int n = 0; n < 4; ++n)
      b[n] = *(const short8*)&Bs[((wc << 6) + (n << 4) + r) * 32 + (kg << 3)];
    #pragma unroll
    for (int m = 0; m < 4; ++m)
      #pragma unroll
      for (int n = 0; n < 4; ++n)
        acc[m][n] = __builtin_amdgcn_mfma_f32_16x16x32_bf16(a[m], b[n], acc[m][n], 0, 0, 0);
  }

  #pragma unroll
  for (int m = 0; m < 4; ++m) {
    #pragma unroll
    for (int n = 0; n < 4; ++n) {
      const int col = bcol + (wc << 6) + (n << 4) + r;
      const float bv = bias[col];
      #pragma unroll
      for (int i = 0; i < 4; ++i) {
        const int row = brow + (wr << 6) + (m << 4) + (kg << 2) + i;
        Hc[(size_t)row * N + col] = f2bu(fmaxf(acc[m][n][i] + bv, 0.f));
      }
    }
  }
}

// ---------- MoE GEMM 2: compact H @ W2^T + b2, scatter-store MOE_slot[token] = v*prob ----------
__global__ __launch_bounds__(256) void gemm_moe2(
    const u16* __restrict__ Hc,       // compact [8192][2048]
    const u16* __restrict__ Bt,       // We2_e [1024][2048]
    const float* __restrict__ bias,   // eb2_e [1024]
    float* __restrict__ MOE0, float* __restrict__ MOE1,
    const int* __restrict__ tok, const float* __restrict__ prob,
    const int* __restrict__ slot, const int* __restrict__ cntPtr)
{
  const int cnt = *cntPtr;
  const int brow = blockIdx.y << 7;
  if (brow >= ((cnt + 127) & ~127)) return;
  const int K = 2048, N = 1024;
  __shared__ __align__(16) u16 As[128 * 32];
  __shared__ __align__(16) u16 Bs[128 * 32];
  const int tid = threadIdx.x;
  const int wave = tid >> 6, lane = tid & 63;
  const int wr = wave >> 1, wc = wave & 1;
  const int bcol = blockIdx.x << 7;
  const int r = lane & 15, kg = lane >> 4;

  f32x4 acc[4][4];
  #pragma unroll
  for (int m = 0; m < 4; ++m)
    #pragma unroll
    for (int n = 0; n < 4; ++n) acc[m][n] = f32x4{0.f, 0.f, 0.f, 0.f};

  const u16* Ab = Hc + (size_t)brow * K;
  const u16* Bb = Bt + (size_t)bcol * K;
  const int c0 = (wave << 6) + lane;
  const int row0 = c0 >> 2, col0 = (c0 & 3) << 3;
  const int c1 = 256 + c0;
  const int row1 = c1 >> 2, col1 = (c1 & 3) << 3;

  for (int k0 = 0; k0 < K; k0 += 32) {
    __syncthreads();
    gload16(Ab + (size_t)row0 * K + k0 + col0, &As[(wave << 6) * 8]);
    gload16(Bb + (size_t)row0 * K + k0 + col0, &Bs[(wave << 6) * 8]);
    gload16(Ab + (size_t)row1 * K + k0 + col1, &As[(256 + (wave << 6)) * 8]);
    gload16(Bb + (size_t)row1 * K + k0 + col1, &Bs[(256 + (wave << 6)) * 8]);
    __syncthreads();
    short8 a[4], b[4];
    #pragma unroll
    for (int m = 0; m < 4; ++m)
      a[m] = *(const short8*)&As[((wr << 6) + (m << 4) + r) * 32 + (kg << 3)];
    #pragma unroll
    for (int n = 0; n < 4; ++n)
      b[n] = *(const short8*)&Bs[((wc << 6) + (n << 4) + r) * 32 + (kg << 3)];
    #pragma unroll
    for (int m = 0; m < 4; ++m)
      #pragma unroll
      for (int n = 0; n < 4; ++n)
        acc[m][n] = __builtin_amdgcn_mfma_f32_16x16x32_bf16(a[m], b[n], acc[m][n], 0, 0, 0);
  }

  #pragma unroll
  for (int m = 0; m < 4; ++m) {
    #pragma unroll
    for (int i = 0; i < 4; ++i) {
      const int row = brow + (wr << 6) + (m << 4) + (kg << 2) + i;
      if (row < cnt) {
        const int t = tok[row];
        const float pp = prob[row];
        float* dst = slot[row] ? MOE1 : MOE0;
        #pragma unroll
        for (int n = 0; n < 4; ++n) {
          const int col = bcol + (wc << 6) + (n << 4) + r;
          dst[(size_t)t * N + col] = (acc[m][n][i] + bias[col]) * pp;
        }
      }
    }
  }
}

// ---------- transpose + convert: src f32 [K,N] -> dst bf16 [N,K]; grid.z batches ----------
__global__ __launch_bounds__(256) void tconv_kernel(const float* __restrict__ src, u16* __restrict__ dst,
                                                    int K, int N)
{
  __shared__ float t[32][33];
  const size_t moff = (size_t)blockIdx.z * K * N;
  const float* s = src + moff;
  u16* d = dst + moff;
  const int n0 = blockIdx.x << 5, k0 = blockIdx.y << 5;
  const int x = threadIdx.x, y = threadIdx.y;
  #pragma unroll
  for (int j = 0; j < 4; ++j) t[y + 8 * j][x] = s[(size_t)(k0 + y + 8 * j) * N + n0 + x];
  __syncthreads();
  #pragma unroll
  for (int j = 0; j < 4; ++j) d[(size_t)(n0 + y + 8 * j) * K + k0 + x] = f2bu(t[x][y + 8 * j]);
}

// ---------- f32 -> bf16 elementwise (4/thread, exact grid) ----------
__global__ __launch_bounds__(256) void conv_kernel(const float* __restrict__ in, u16* __restrict__ out)
{
  const size_t i = ((size_t)blockIdx.x * 256 + threadIdx.x) * 4;
  float4 v = *(const float4*)(in + i);
  *(ushort4*)(out + i) = make_ushort4(f2bu(v.x), f2bu(v.y), f2bu(v.z), f2bu(v.w));
}

// ---------- add sinusoidal positional encoding; write f32 + bf16 ----------
__global__ __launch_bounds__(256) void pe_kernel(float* __restrict__ X, u16* __restrict__ Xb)
{
  const int idx = blockIdx.x * 256 + threadIdx.x;
  const int d = idx & 1023;
  const int s = (idx >> 10) & 127;
  const float de = (float)(d & ~1);
  const float ang = (float)s * expf(de * (-9.210340371976184f / 1024.f));
  const float pe = (d & 1) ? cosf(ang) : sinf(ang);
  const float v = X[idx] + pe;
  X[idx] = v;
  Xb[idx] = f2bu(v);
}

// ---------- fused residual + layernorm (1 residual); write f32 + bf16 ----------
__global__ __launch_bounds__(256) void ln_kernel(const float* __restrict__ Xi, const float* __restrict__ R,
    const float* __restrict__ g, const float* __restrict__ be,
    float* __restrict__ Xo, u16* __restrict__ Xbo)
{
  const size_t base = (size_t)blockIdx.x << 10;
  const int tid = threadIdx.x;
  float vals[4]; float s = 0.f, s2 = 0.f;
  #pragma unroll
  for (int j = 0; j < 4; ++j) {
    const int d = tid + (j << 8);
    const float v = Xi[base + d] + R[base + d];
    vals[j] = v; s += v; s2 += v * v;
  }
  s = waveRedSum(s); s2 = waveRedSum(s2);
  __shared__ float rs[4], rs2[4];
  const int wave = tid >> 6, lane = tid & 63;
  if (lane == 0) { rs[wave] = s; rs2[wave] = s2; }
  __syncthreads();
  s = rs[0] + rs[1] + rs[2] + rs[3];
  s2 = rs2[0] + rs2[1] + rs2[2] + rs2[3];
  const float mean = s * (1.f / 1024.f);
  const float var = s2 * (1.f / 1024.f) - mean * mean;
  const float inv = rsqrtf(var + 1e-5f);
  #pragma unroll
  for (int j = 0; j < 4; ++j) {
    const int d = tid + (j << 8);
    const float y = (vals[j] - mean) * inv * g[d] + be[d];
    Xo[base + d] = y;
    Xbo[base + d] = f2bu(y);
  }
}

// ---------- fused residual + layernorm (2 residuals: MOE slots) ----------
__global__ __launch_bounds__(256) void ln2_kernel(const float* __restrict__ Xi,
    const float* __restrict__ R0, const float* __restrict__ R1,
    const float* __restrict__ g, const float* __restrict__ be,
    float* __restrict__ Xo, u16* __restrict__ Xbo)
{
  const size_t base = (size_t)blockIdx.x << 10;
  const int tid = threadIdx.x;
  float vals[4]; float s = 0.f, s2 = 0.f;
  #pragma unroll
  for (int j = 0; j < 4; ++j) {
    const int d = tid + (j << 8);
    const float v = Xi[base + d] + (R0[base + d] + R1[base + d]);
    vals[j] = v; s += v; s2 += v * v;
  }
  s = waveRedSum(s); s2 = waveRedSum(s2);
  __shared__ float rs[4], rs2[4];
  const int wave = tid >> 6, lane = tid & 63;
  if (lane == 0) { rs[wave] = s; rs2[wave] = s2; }
  __syncthreads();
  s = rs[0] + rs[1] + rs[2] + rs[3];
  s2 = rs2[0] + rs2[1] + rs2[2] + rs2[3];
  const float mean = s * (1.f / 1024.f);
  const float var = s2 * (1.f / 1024.f) - mean * mean;
  const float inv = rsqrtf(var + 1e-5f);
  #pragma unroll
  for (int j = 0; j < 4; ++j) {
    const int d = tid + (j << 8);
    const float y = (vals[j] - mean) * inv * g[d] + be[d];
    Xo[base + d] = y;
    Xbo[base + d] = f2bu(y);
  }
}

// ---------- MFMA attention per (b,h): 4 waves, each owns 32 Q-rows; bf16 QKV input ----------
#define LDW 136
__global__ __launch_bounds__(256) void attn_mfma_kernel(const u16* __restrict__ QKVb, u16* __restrict__ ATTb)
{
  __shared__ __align__(16) u16 Kb[128 * LDW];   // [key][d]
  __shared__ __align__(16) u16 Vt[128 * LDW];   // [d][key]
  __shared__ __align__(16) u16 Pb[128 * LDW];   // [q][key] (wave-private rows)
  const int b = blockIdx.x >> 3, h = blockIdx.x & 7;
  const int tid = threadIdx.x;
  const int wave = tid >> 6, lane = tid & 63;
  const int r = lane & 15, kg = lane >> 4;
  const u16* base = QKVb + (size_t)b * 128 * 3072 + h * 128;

  // stage K row-major (vector copies)
  for (int i = tid; i < 128 * 16; i += 256) {
    const int row = i >> 4, c8 = (i & 15) << 3;
    *(short8*)&Kb[row * LDW + c8] = *(const short8*)(base + (size_t)row * 3072 + 1024 + c8);
  }
  // stage V transposed
  for (int i = tid; i < 128 * 128; i += 256) {
    const int d = i & 127, key = i >> 7;
    Vt[d * LDW + key] = base[(size_t)key * 3072 + 2048 + d];
  }

  // Q fragments straight from global (rows wave*32 .. +32)
  short8 a[2][4];
  #pragma unroll
  for (int m = 0; m < 2; ++m) {
    const int row = wave * 32 + m * 16 + r;
    const u16* qp = base + (size_t)row * 3072;
    #pragma unroll
    for (int ks = 0; ks < 4; ++ks)
      a[m][ks] = *(const short8*)(qp + ks * 32 + kg * 8);
  }
  __syncthreads();

  // QK^T
  f32x4 acc[2][8];
  #pragma unroll
  for (int m = 0; m < 2; ++m)
    #pragma unroll
    for (int n = 0; n < 8; ++n) acc[m][n] = f32x4{0.f, 0.f, 0.f, 0.f};
  #pragma unroll
  for (int n = 0; n < 8; ++n) {
    #pragma unroll
    for (int ks = 0; ks < 4; ++ks) {
      short8 bf = *(const short8*)&Kb[(n * 16 + r) * LDW + ks * 32 + kg * 8];
      #pragma unroll
      for (int m = 0; m < 2; ++m)
        acc[m][n] = __builtin_amdgcn_mfma_f32_16x16x32_bf16(a[m][ks], bf, acc[m][n], 0, 0, 0);
    }
  }

  // row softmax (reduce over r across 16 lanes)
  const float sc = 0.08838834764831845f;  // 1/sqrt(128)
  #pragma unroll
  for (int m = 0; m < 2; ++m) {
    #pragma unroll
    for (int i = 0; i < 4; ++i) {
      float mx = -1e30f;
      #pragma unroll
      for (int n = 0; n < 8; ++n) mx = fmaxf(mx, acc[m][n][i]);
      #pragma unroll
      for (int msk = 1; msk < 16; msk <<= 1) mx = fmaxf(mx, __shfl_xor(mx, msk, 64));
      float s = 0.f;
      #pragma unroll
      for (int n = 0; n < 8; ++n) { float pv = __expf((acc[m][n][i] - mx) * sc); acc[m][n][i] = pv; s += pv; }
      #pragma unroll
      for (int msk = 1; msk < 16; msk <<= 1) s += __shfl_xor(s, msk, 64);
      const float inv = 1.f / s;
      #pragma unroll
      for (int n = 0; n < 8; ++n) {
        const int prow = wave * 32 + m * 16 + kg * 4 + i;
        Pb[prow * LDW + n * 16 + r] = f2bu(acc[m][n][i] * inv);
      }
    }
  }
  // Pb rows are wave-private: no barrier needed

  // PV
  f32x4 oacc[2][8];
  #pragma unroll
  for (int m = 0; m < 2; ++m)
    #pragma unroll
    for (int n = 0; n < 8; ++n) oacc[m][n] = f32x4{0.f, 0.f, 0.f, 0.f};
  #pragma unroll
  for (int ks = 0; ks < 4; ++ks) {
    short8 pa[2];
    #pragma unroll
    for (int m = 0; m < 2; ++m)
      pa[m] = *(const short8*)&Pb[(wave * 32 + m * 16 + r) * LDW + ks * 32 + kg * 8];
    #pragma unroll
    for (int n = 0; n < 8; ++n) {
      short8 vb = *(const short8*)&Vt[(n * 16 + r) * LDW + ks * 32 + kg * 8];
      #pragma unroll
      for (int m = 0; m < 2; ++m)
        oacc[m][n] = __builtin_amdgcn_mfma_f32_16x16x32_bf16(pa[m], vb, oacc[m][n], 0, 0, 0);
    }
  }

  u16* op = ATTb + ((size_t)b * 128) * 1024 + h * 128;
  #pragma unroll
  for (int m = 0; m < 2; ++m) {
    #pragma unroll
    for (int n = 0; n < 8; ++n) {
      #pragma unroll
      for (int i = 0; i < 4; ++i) {
        const int row = wave * 32 + m * 16 + kg * 4 + i;
        op[(size_t)row * 1024 + n * 16 + r] = f2bu(oacc[m][n][i]);
      }
    }
  }
}
#undef LDW

// ---------- router: logits, top-2, softmax -> per-expert token lists ----------
__global__ __launch_bounds__(256) void router_kernel(const float* __restrict__ X, const float* __restrict__ rw,
    const float* __restrict__ rb, int* __restrict__ cnt,
    int* __restrict__ tok, float* __restrict__ prob, int* __restrict__ slot)
{
  const int token = blockIdx.x * 4 + (threadIdx.x >> 6);
  const int lane = threadIdx.x & 63;
  const float* xp = X + ((size_t)token << 10);
  float a0 = 0, a1 = 0, a2 = 0, a3 = 0;
  #pragma unroll
  for (int j = 0; j < 16; ++j) {
    const int k = lane + (j << 6);
    const float x = xp[k];
    const float4 w = *(const float4*)(rw + ((size_t)k << 2));
    a0 += x * w.x; a1 += x * w.y; a2 += x * w.z; a3 += x * w.w;
  }
  a0 = waveRedSum(a0); a1 = waveRedSum(a1); a2 = waveRedSum(a2); a3 = waveRedSum(a3);
  if (lane == 0) {
    float v[4] = {a0 + rb[0], a1 + rb[1], a2 + rb[2], a3 + rb[3]};
    int i1 = 0;
    for (int e = 1; e < 4; ++e) if (v[e] > v[i1]) i1 = e;       // earliest max (top_k tie rule)
    int i2 = (i1 == 0) ? 1 : 0;
    for (int e = 0; e < 4; ++e) if (e != i1 && v[e] > v[i2]) i2 = e;
    const float p2 = __expf(v[i2] - v[i1]);
    const float is = 1.f / (1.f + p2);
    int pos1 = atomicAdd(cnt + i1, 1);
    tok[i1 * 8192 + pos1] = token; prob[i1 * 8192 + pos1] = is; slot[i1 * 8192 + pos1] = 0;
    int pos2 = atomicAdd(cnt + i2, 1);
    tok[i2 * 8192 + pos2] = token; prob[i2 * 8192 + pos2] = p2 * is; slot[i2 * 8192 + pos2] = 1;
  }
}

// ---------- pooling score ----------
__global__ __launch_bounds__(256) void score_kernel(const float* __restrict__ X, const float* __restrict__ aw,
    const float* __restrict__ ab, float* __restrict__ S)
{
  const int token = blockIdx.x * 4 + (threadIdx.x >> 6);
  const int lane = threadIdx.x & 63;
  const float* xp = X + ((size_t)token << 10);
  float s = 0.f;
  #pragma unroll
  for (int j = 0; j < 16; ++j) { const int k = lane + (j << 6); s += xp[k] * aw[k]; }
  s = waveRedSum(s);
  if (lane == 0) S[token] = s + ab[0];
}

// ---------- softmax over S per batch + weighted pool ----------
__global__ __launch_bounds__(256) void pool_kernel(const float* __restrict__ X, const float* __restrict__ S,
                                                   float* __restrict__ P)
{
  const int b = blockIdx.x;
  const int tid = threadIdx.x;
  __shared__ float p[128];
  if (tid < 128) p[tid] = S[b * 128 + tid];
  __syncthreads();
  float mx = -1e30f;
  for (int t = 0; t < 128; ++t) mx = fmaxf(mx, p[t]);
  float sum = 0.f;
  for (int t = 0; t < 128; ++t) sum += __expf(p[t] - mx);
  const float inv = 1.f / sum;
  __syncthreads();
  if (tid < 128) p[tid] = __expf(p[tid] - mx) * inv;
  __syncthreads();
  float acc[4] = {0.f, 0.f, 0.f, 0.f};
  for (int t = 0; t < 128; ++t) {
    const float pt = p[t];
    const float* xp = X + ((size_t)(b * 128 + t) << 10) + tid;
    #pragma unroll
    for (int j = 0; j < 4; ++j) acc[j] += pt * xp[j << 8];
  }
  #pragma unroll
  for (int j = 0; j < 4; ++j) P[((size_t)b << 10) + tid + (j << 8)] = acc[j];
}

// ---------- task heads ----------
__global__ __launch_bounds__(256) void heads_kernel(const float* __restrict__ P, const float* __restrict__ hw,
    const float* __restrict__ hb, float* __restrict__ out)
{
  const int idx = blockIdx.x * 4 + (threadIdx.x >> 6);
  const int lane = threadIdx.x & 63;
  const int t = idx >> 8, b = (idx >> 2) & 63, c = idx & 3;
  const float* pp = P + ((size_t)b << 10);
  const float* wp = hw + (size_t)t * 4096 + c;
  float s = 0.f;
  #pragma unroll
  for (int j = 0; j < 16; ++j) { const int k = lane + (j << 6); s += pp[k] * wp[(size_t)k << 2]; }
  s = waveRedSum(s);
  if (lane == 0) out[idx] = s + hb[t * 4 + c];
}

// ---------- host ----------
extern "C" void kernel_launch(void* const* d_in, const int* in_sizes, int n_in,
                              void* d_out, int out_size, void* d_ws, size_t ws_size,
                              hipStream_t stream)
{
  (void)in_sizes; (void)n_in; (void)out_size; (void)ws_size;
  const float* vis        = (const float*)d_in[0];
  const float* proj_w     = (const float*)d_in[1];
  const float* proj_b     = (const float*)d_in[2];
  const float* in_proj_w  = (const float*)d_in[3];
  const float* in_proj_b  = (const float*)d_in[4];
  const float* out_proj_w = (const float*)d_in[5];
  const float* out_proj_b = (const float*)d_in[6];
  const float* ln1_g      = (const float*)d_in[7];
  const float* ln1_b      = (const float*)d_in[8];
  const float* ln2_g      = (const float*)d_in[9];
  const float* ln2_b      = (const float*)d_in[10];
  const float* router_w   = (const float*)d_in[11];
  const float* router_b   = (const float*)d_in[12];
  const float* ew1        = (const float*)d_in[13];
  const float* eb1        = (const float*)d_in[14];
  const float* ew2        = (const float*)d_in[15];
  const float* eb2        = (const float*)d_in[16];
  const float* attn_w     = (const float*)d_in[17];
  const float* attn_b     = (const float*)d_in[18];
  const float* heads_w    = (const float*)d_in[19];
  const float* heads_b    = (const float*)d_in[20];
  float* out = (float*)d_out;

  char* p = (char*)d_ws;
  auto take = [&](size_t bytes) -> char* {
    char* q = p; p += (bytes + 255) & ~(size_t)255; return q;
  };
  float* X    = (float*)take(8192ULL * 1024 * 4);
  u16*   Xb   = (u16*)  take(8192ULL * 1024 * 2);
  char*  QKVr = take(8192ULL * 3072 * 4);        // region: QKVb | O, MOE0, MOE1
  u16*   ATTb = (u16*)  take(8192ULL * 1024 * 2);
  u16*   H    = (u16*)  take(8192ULL * 2048 * 2);
  int*   CNT  = (int*)  take(4 * 4);
  int*   TOK  = (int*)  take(4ULL * 8192 * 4);
  float* PROB = (float*)take(4ULL * 8192 * 4);
  int*   SLOT = (int*)  take(4ULL * 8192 * 4);
  float* S    = (float*)take(8192ULL * 4);
  float* POOL = (float*)take(64ULL * 1024 * 4);
  u16*   Wqkv = (u16*)  take(3072ULL * 1024 * 2);
  u16*   Wout = (u16*)  take(1024ULL * 1024 * 2);
  u16*   We1  = (u16*)  take(4ULL * 2048 * 1024 * 2);
  u16*   We2  = (u16*)  take(4ULL * 1024 * 2048 * 2);
  // aliases into QKV region (QKVb dead after attn; O dead after ln1)
  u16*   QKVb = (u16*)QKVr;                               // 50.3 MB
  float* O    = (float*)QKVr;                             // 33.5 MB
  float* MOE0 = (float*)(QKVr + 33554432);                // 33.5 MB
  float* MOE1 = (float*)(QKVr + 67108864);                // 33.5 MB
  u16*   Wproj = We1;                  // used before layer 0 overwrites We1
  u16*   VISb  = H;                    // vis bf16 (25.2MB <= 33.5MB)

  const dim3 tb(32, 8);

  // projection: X = vis @ proj_w + proj_b
  tconv_kernel<<<dim3(1024 / 32, 1536 / 32, 1), tb, 0, stream>>>(proj_w, Wproj, 1536, 1024);
  conv_kernel<<<(8192 * 1536 / 4) / 256, 256, 0, stream>>>(vis, VISb);
  gemm_bt<0><<<dim3(8, 64), 256, 0, stream>>>(VISb, Wproj, proj_b, X, nullptr, 1024, 1536);
  pe_kernel<<<8192 * 1024 / 256, 256, 0, stream>>>(X, Xb);

  for (int l = 0; l < 4; ++l) {
    tconv_kernel<<<dim3(3072 / 32, 1024 / 32, 1), tb, 0, stream>>>(in_proj_w + (size_t)l * 1024 * 3072, Wqkv, 1024, 3072);
    tconv_kernel<<<dim3(1024 / 32, 1024 / 32, 1), tb, 0, stream>>>(out_proj_w + (size_t)l * 1024 * 1024, Wout, 1024, 1024);
    tconv_kernel<<<dim3(2048 / 32, 1024 / 32, 4), tb, 0, stream>>>(ew1 + (size_t)l * 4 * 1024 * 2048, We1, 1024, 2048);
    tconv_kernel<<<dim3(1024 / 32, 2048 / 32, 4), tb, 0, stream>>>(ew2 + (size_t)l * 4 * 2048 * 1024, We2, 2048, 1024);

    gemm_bt<2><<<dim3(24, 64), 256, 0, stream>>>(Xb, Wqkv, in_proj_b + l * 3072, nullptr, QKVb, 3072, 1024);
    attn_mfma_kernel<<<512, 256, 0, stream>>>(QKVb, ATTb);
    gemm_bt<0><<<dim3(8, 64), 256, 0, stream>>>(ATTb, Wout, out_proj_b + l * 1024, O, nullptr, 1024, 1024);
    ln_kernel<<<8192, 256, 0, stream>>>(X, O, ln1_g + l * 1024, ln1_b + l * 1024, X, Xb);

    hipMemsetAsync(CNT, 0, 16, stream);
    router_kernel<<<2048, 256, 0, stream>>>(X, router_w + l * 4096, router_b + l * 4, CNT, TOK, PROB, SLOT);
    for (int e = 0; e < 4; ++e) {
      gemm_moe1<<<dim3(16, 64), 256, 0, stream>>>(Xb, We1 + (size_t)e * 2048 * 1024,
          eb1 + (size_t)(l * 4 + e) * 2048, H, TOK + e * 8192, CNT + e);
      gemm_moe2<<<dim3(8, 64), 256, 0, stream>>>(H, We2 + (size_t)e * 1024 * 2048,
          eb2 + (size_t)(l * 4 + e) * 1024, MOE0, MOE1,
          TOK + e * 8192, PROB + e * 8192, SLOT + e * 8192, CNT + e);
    }
    ln2_kernel<<<8192, 256, 0, stream>>>(X, MOE0, MOE1, ln2_g + l * 1024, ln2_b + l * 1024, X, Xb);
  }

  score_kernel<<<2048, 256, 0, stream>>>(X, attn_w, attn_b, S);
  pool_kernel<<<64, 256, 0, stream>>>(X, S, POOL);
  heads_kernel<<<256, 256, 0, stream>>>(POOL, heads_w, heads_b, out);
}

// Round 4
// 2258.246 us; speedup vs baseline: 1.6134x; 1.2976x over previous
//
#include <hip/hip_runtime.h>
#include <hip/hip_bf16.h>

typedef unsigned short u16;
typedef unsigned int u32;
using short8 = __attribute__((ext_vector_type(8))) short;
using f32x4  = __attribute__((ext_vector_type(4))) float;

// ---------- helpers ----------
__device__ __forceinline__ u16 f2bu(float f) {            // f32 -> bf16 bits (RNE)
  u32 u = __builtin_bit_cast(u32, f);
  u32 r = u + 0x7fffu + ((u >> 16) & 1u);
  return (u16)(r >> 16);
}
__device__ __forceinline__ float bu2f(u16 u) {             // bf16 bits -> f32
  u32 x = ((u32)u) << 16;
  return __builtin_bit_cast(float, x);
}
__device__ __forceinline__ float waveRedSum(float v) {
  #pragma unroll
  for (int off = 32; off > 0; off >>= 1) v += __shfl_xor(v, off, 64);
  return v;
}
__device__ __forceinline__ void gload16(const void* g, void* l) {
  __builtin_amdgcn_global_load_lds((const __attribute__((address_space(1))) u32*)g,
                                   (__attribute__((address_space(3))) u32*)l, 16, 0, 0);
}

// ---------- GEMM: C[M,N] = A[M,K](bf16) * Bt[N,K](bf16)^T + bias ----------
// MODE 0: C f32 = acc+bias | MODE 2: Cb bf16 = acc+bias
template<int MODE>
__global__ __launch_bounds__(256) void gemm_bt(
    const u16* __restrict__ A, const u16* __restrict__ Bt,
    const float* __restrict__ bias,
    float* __restrict__ C, u16* __restrict__ Cb, int N, int K)
{
  __shared__ __align__(16) u16 As[128 * 32];
  __shared__ __align__(16) u16 Bs[128 * 32];
  const int tid = threadIdx.x;
  const int wave = tid >> 6, lane = tid & 63;
  const int wr = wave >> 1, wc = wave & 1;
  const int brow = blockIdx.y << 7, bcol = blockIdx.x << 7;
  const int r = lane & 15, kg = lane >> 4;

  f32x4 acc[4][4];
  #pragma unroll
  for (int m = 0; m < 4; ++m)
    #pragma unroll
    for (int n = 0; n < 4; ++n) acc[m][n] = f32x4{0.f, 0.f, 0.f, 0.f};

  const u16* Ab = A + (size_t)brow * K;
  const u16* Bb = Bt + (size_t)bcol * K;
  const int c0 = (wave << 6) + lane;
  const int row0 = c0 >> 2, col0 = (c0 & 3) << 3;
  const int c1 = 256 + c0;
  const int row1 = c1 >> 2, col1 = (c1 & 3) << 3;

  for (int k0 = 0; k0 < K; k0 += 32) {
    __syncthreads();
    gload16(Ab + (size_t)row0 * K + k0 + col0, &As[(wave << 6) * 8]);
    gload16(Bb + (size_t)row0 * K + k0 + col0, &Bs[(wave << 6) * 8]);
    gload16(Ab + (size_t)row1 * K + k0 + col1, &As[(256 + (wave << 6)) * 8]);
    gload16(Bb + (size_t)row1 * K + k0 + col1, &Bs[(256 + (wave << 6)) * 8]);
    __syncthreads();
    short8 a[4], b[4];
    #pragma unroll
    for (int m = 0; m < 4; ++m)
      a[m] = *(const short8*)&As[((wr << 6) + (m << 4) + r) * 32 + (kg << 3)];
    #pragma unroll
    for (int n = 0; n < 4; ++n)
      b[n] = *(const short8*)&Bs[((wc << 6) + (n << 4) + r) * 32 + (kg << 3)];
    #pragma unroll
    for (int m = 0; m < 4; ++m)
      #pragma unroll
      for (int n = 0; n < 4; ++n)
        acc[m][n] = __builtin_amdgcn_mfma_f32_16x16x32_bf16(a[m], b[n], acc[m][n], 0, 0, 0);
  }

  #pragma unroll
  for (int m = 0; m < 4; ++m) {
    #pragma unroll
    for (int n = 0; n < 4; ++n) {
      const int col = bcol + (wc << 6) + (n << 4) + r;
      const float bv = bias[col];
      #pragma unroll
      for (int i = 0; i < 4; ++i) {
        const int row = brow + (wr << 6) + (m << 4) + (kg << 2) + i;
        float v = acc[m][n][i] + bv;
        const size_t off = (size_t)row * N + col;
        if constexpr (MODE == 0) C[off] = v;
        else Cb[off] = f2bu(v);
      }
    }
  }
}

// ---------- MoE GEMM 1: gather rows of A by token list; H = relu(A[tok] @ W1^T + b1), bf16 compact ----------
__global__ __launch_bounds__(256) void gemm_moe1(
    const u16* __restrict__ A,        // Xb [8192][1024]
    const u16* __restrict__ Bt,       // We1_e [2048][1024]
    const float* __restrict__ bias,   // eb1_e [2048]
    u16* __restrict__ Hc,             // compact H [8192][2048]
    const int* __restrict__ tok, const int* __restrict__ cntPtr)
{
  const int cnt = *cntPtr;
  const int brow = blockIdx.y << 7;
  if (brow >= ((cnt + 127) & ~127)) return;
  const int K = 1024, N = 2048;
  __shared__ __align__(16) u16 As[128 * 32];
  __shared__ __align__(16) u16 Bs[128 * 32];
  const int tid = threadIdx.x;
  const int wave = tid >> 6, lane = tid & 63;
  const int wr = wave >> 1, wc = wave & 1;
  const int bcol = blockIdx.x << 7;
  const int r = lane & 15, kg = lane >> 4;

  f32x4 acc[4][4];
  #pragma unroll
  for (int m = 0; m < 4; ++m)
    #pragma unroll
    for (int n = 0; n < 4; ++n) acc[m][n] = f32x4{0.f, 0.f, 0.f, 0.f};

  const u16* Bb = Bt + (size_t)bcol * K;
  const int c0 = (wave << 6) + lane;
  const int row0 = c0 >> 2, col0 = (c0 & 3) << 3;
  const int c1 = 256 + c0;
  const int row1 = c1 >> 2, col1 = (c1 & 3) << 3;
  const int t0 = (brow + row0 < cnt) ? tok[brow + row0] : 0;
  const int t1 = (brow + row1 < cnt) ? tok[brow + row1] : 0;

  for (int k0 = 0; k0 < K; k0 += 32) {
    __syncthreads();
    gload16(A + (size_t)t0 * K + k0 + col0, &As[(wave << 6) * 8]);
    gload16(Bb + (size_t)row0 * K + k0 + col0, &Bs[(wave << 6) * 8]);
    gload16(A + (size_t)t1 * K + k0 + col1, &As[(256 + (wave << 6)) * 8]);
    gload16(Bb + (size_t)row1 * K + k0 + col1, &Bs[(256 + (wave << 6)) * 8]);
    __syncthreads();
    short8 a[4], b[4];
    #pragma unroll
    for (int m = 0; m < 4; ++m)
      a[m] = *(const short8*)&As[((wr << 6) + (m << 4) + r) * 32 + (kg << 3)];
    #pragma unroll
    for (int n = 0; n < 4; ++n)
      b[n] = *(const short8*)&Bs[((wc << 6) + (n << 4) + r) * 32 + (kg << 3)];
    #pragma unroll
    for (int m = 0; m < 4; ++m)
      #pragma unroll
      for (int n = 0; n < 4; ++n)
        acc[m][n] = __builtin_amdgcn_mfma_f32_16x16x32_bf16(a[m], b[n], acc[m][n], 0, 0, 0);
  }

  #pragma unroll
  for (int m = 0; m < 4; ++m) {
    #pragma unroll
    for (int n = 0; n < 4; ++n) {
      const int col = bcol + (wc << 6) + (n << 4) + r;
      const float bv = bias[col];
      #pragma unroll
      for (int i = 0; i < 4; ++i) {
        const int row = brow + (wr << 6) + (m << 4) + (kg << 2) + i;
        Hc[(size_t)row * N + col] = f2bu(fmaxf(acc[m][n][i] + bv, 0.f));
      }
    }
  }
}

// ---------- MoE GEMM 2: compact H @ W2^T + b2, scatter-store MOE_slot[token] = v*prob ----------
__global__ __launch_bounds__(256) void gemm_moe2(
    const u16* __restrict__ Hc,       // compact [8192][2048]
    const u16* __restrict__ Bt,       // We2_e [1024][2048]
    const float* __restrict__ bias,   // eb2_e [1024]
    float* __restrict__ MOE0, float* __restrict__ MOE1,
    const int* __restrict__ tok, const float* __restrict__ prob,
    const int* __restrict__ slot, const int* __restrict__ cntPtr)
{
  const int cnt = *cntPtr;
  const int brow = blockIdx.y << 7;
  if (brow >= ((cnt + 127) & ~127)) return;
  const int K = 2048, N = 1024;
  __shared__ __align__(16) u16 As[128 * 32];
  __shared__ __align__(16) u16 Bs[128 * 32];
  const int tid = threadIdx.x;
  const int wave = tid >> 6, lane = tid & 63;
  const int wr = wave >> 1, wc = wave & 1;
  const int bcol = blockIdx.x << 7;
  const int r = lane & 15, kg = lane >> 4;

  f32x4 acc[4][4];
  #pragma unroll
  for (int m = 0; m < 4; ++m)
    #pragma unroll
    for (int n = 0; n < 4; ++n) acc[m][n] = f32x4{0.f, 0.f, 0.f, 0.f};

  const u16* Ab = Hc + (size_t)brow * K;
  const u16* Bb = Bt + (size_t)bcol * K;
  const int c0 = (wave << 6) + lane;
  const int row0 = c0 >> 2, col0 = (c0 & 3) << 3;
  const int c1 = 256 + c0;
  const int row1 = c1 >> 2, col1 = (c1 & 3) << 3;

  for (int k0 = 0; k0 < K; k0 += 32) {
    __syncthreads();
    gload16(Ab + (size_t)row0 * K + k0 + col0, &As[(wave << 6) * 8]);
    gload16(Bb + (size_t)row0 * K + k0 + col0, &Bs[(wave << 6) * 8]);
    gload16(Ab + (size_t)row1 * K + k0 + col1, &As[(256 + (wave << 6)) * 8]);
    gload16(Bb + (size_t)row1 * K + k0 + col1, &Bs[(256 + (wave << 6)) * 8]);
    __syncthreads();
    short8 a[4], b[4];
    #pragma unroll
    for (int m = 0; m < 4; ++m)
      a[m] = *(const short8*)&As[((wr << 6) + (m << 4) + r) * 32 + (kg << 3)];
    #pragma unroll
    for (int n = 0; n < 4; ++n)
      b[n] = *(const short8*)&Bs[((wc << 6) + (n << 4) + r) * 32 + (kg << 3)];
    #pragma unroll
    for (int m = 0; m < 4; ++m)
      #pragma unroll
      for (int n = 0; n < 4; ++n)
        acc[m][n] = __builtin_amdgcn_mfma_f32_16x16x32_bf16(a[m], b[n], acc[m][n], 0, 0, 0);
  }

  #pragma unroll
  for (int m = 0; m < 4; ++m) {
    #pragma unroll
    for (int i = 0; i < 4; ++i) {
      const int row = brow + (wr << 6) + (m << 4) + (kg << 2) + i;
      if (row < cnt) {
        const int t = tok[row];
        const float pp = prob[row];
        float* dst = slot[row] ? MOE1 : MOE0;
        #pragma unroll
        for (int n = 0; n < 4; ++n) {
          const int col = bcol + (wc << 6) + (n << 4) + r;
          dst[(size_t)t * N + col] = (acc[m][n][i] + bias[col]) * pp;
        }
      }
    }
  }
}

// ---------- transpose + convert: src f32 [K,N] -> dst bf16 [N,K]; grid.z batches ----------
__global__ __launch_bounds__(256) void tconv_kernel(const float* __restrict__ src, u16* __restrict__ dst,
                                                    int K, int N)
{
  __shared__ float t[32][33];
  const size_t moff = (size_t)blockIdx.z * K * N;
  const float* s = src + moff;
  u16* d = dst + moff;
  const int n0 = blockIdx.x << 5, k0 = blockIdx.y << 5;
  const int x = threadIdx.x, y = threadIdx.y;
  #pragma unroll
  for (int j = 0; j < 4; ++j) t[y + 8 * j][x] = s[(size_t)(k0 + y + 8 * j) * N + n0 + x];
  __syncthreads();
  #pragma unroll
  for (int j = 0; j < 4; ++j) d[(size_t)(n0 + y + 8 * j) * K + k0 + x] = f2bu(t[x][y + 8 * j]);
}

// ---------- f32 -> bf16 elementwise (4/thread, exact grid) ----------
__global__ __launch_bounds__(256) void conv_kernel(const float* __restrict__ in, u16* __restrict__ out)
{
  const size_t i = ((size_t)blockIdx.x * 256 + threadIdx.x) * 4;
  float4 v = *(const float4*)(in + i);
  *(ushort4*)(out + i) = make_ushort4(f2bu(v.x), f2bu(v.y), f2bu(v.z), f2bu(v.w));
}

// ---------- add sinusoidal positional encoding; write f32 + bf16 ----------
__global__ __launch_bounds__(256) void pe_kernel(float* __restrict__ X, u16* __restrict__ Xb)
{
  const int idx = blockIdx.x * 256 + threadIdx.x;
  const int d = idx & 1023;
  const int s = (idx >> 10) & 127;
  const float de = (float)(d & ~1);
  const float ang = (float)s * expf(de * (-9.210340371976184f / 1024.f));
  const float pe = (d & 1) ? cosf(ang) : sinf(ang);
  const float v = X[idx] + pe;
  X[idx] = v;
  Xb[idx] = f2bu(v);
}

// ---------- fused residual + layernorm (1 residual); write f32 + bf16 ----------
__global__ __launch_bounds__(256) void ln_kernel(const float* __restrict__ Xi, const float* __restrict__ R,
    const float* __restrict__ g, const float* __restrict__ be,
    float* __restrict__ Xo, u16* __restrict__ Xbo)
{
  const size_t base = (size_t)blockIdx.x << 10;
  const int tid = threadIdx.x;
  float vals[4]; float s = 0.f, s2 = 0.f;
  #pragma unroll
  for (int j = 0; j < 4; ++j) {
    const int d = tid + (j << 8);
    const float v = Xi[base + d] + R[base + d];
    vals[j] = v; s += v; s2 += v * v;
  }
  s = waveRedSum(s); s2 = waveRedSum(s2);
  __shared__ float rs[4], rs2[4];
  const int wave = tid >> 6, lane = tid & 63;
  if (lane == 0) { rs[wave] = s; rs2[wave] = s2; }
  __syncthreads();
  s = rs[0] + rs[1] + rs[2] + rs[3];
  s2 = rs2[0] + rs2[1] + rs2[2] + rs2[3];
  const float mean = s * (1.f / 1024.f);
  const float var = s2 * (1.f / 1024.f) - mean * mean;
  const float inv = rsqrtf(var + 1e-5f);
  #pragma unroll
  for (int j = 0; j < 4; ++j) {
    const int d = tid + (j << 8);
    const float y = (vals[j] - mean) * inv * g[d] + be[d];
    Xo[base + d] = y;
    Xbo[base + d] = f2bu(y);
  }
}

// ---------- fused residual + layernorm (2 residuals: MOE slots) ----------
__global__ __launch_bounds__(256) void ln2_kernel(const float* __restrict__ Xi,
    const float* __restrict__ R0, const float* __restrict__ R1,
    const float* __restrict__ g, const float* __restrict__ be,
    float* __restrict__ Xo, u16* __restrict__ Xbo)
{
  const size_t base = (size_t)blockIdx.x << 10;
  const int tid = threadIdx.x;
  float vals[4]; float s = 0.f, s2 = 0.f;
  #pragma unroll
  for (int j = 0; j < 4; ++j) {
    const int d = tid + (j << 8);
    const float v = Xi[base + d] + (R0[base + d] + R1[base + d]);
    vals[j] = v; s += v; s2 += v * v;
  }
  s = waveRedSum(s); s2 = waveRedSum(s2);
  __shared__ float rs[4], rs2[4];
  const int wave = tid >> 6, lane = tid & 63;
  if (lane == 0) { rs[wave] = s; rs2[wave] = s2; }
  __syncthreads();
  s = rs[0] + rs[1] + rs[2] + rs[3];
  s2 = rs2[0] + rs2[1] + rs2[2] + rs2[3];
  const float mean = s * (1.f / 1024.f);
  const float var = s2 * (1.f / 1024.f) - mean * mean;
  const float inv = rsqrtf(var + 1e-5f);
  #pragma unroll
  for (int j = 0; j < 4; ++j) {
    const int d = tid + (j << 8);
    const float y = (vals[j] - mean) * inv * g[d] + be[d];
    Xo[base + d] = y;
    Xbo[base + d] = f2bu(y);
  }
}

// ---------- MFMA attention per (b,h): 4 waves, each owns 32 Q-rows; bf16 QKV input ----------
#define LDW 136
__global__ __launch_bounds__(256) void attn_mfma_kernel(const u16* __restrict__ QKVb, u16* __restrict__ ATTb)
{
  __shared__ __align__(16) u16 Kb[128 * LDW];   // [key][d]
  __shared__ __align__(16) u16 Vt[128 * LDW];   // [d][key]
  __shared__ __align__(16) u16 Pb[128 * LDW];   // [q][key] (wave-private rows)
  const int b = blockIdx.x >> 3, h = blockIdx.x & 7;
  const int tid = threadIdx.x;
  const int wave = tid >> 6, lane = tid & 63;
  const int r = lane & 15, kg = lane >> 4;
  const u16* base = QKVb + (size_t)b * 128 * 3072 + h * 128;

  // stage K row-major (vector copies)
  for (int i = tid; i < 128 * 16; i += 256) {
    const int row = i >> 4, c8 = (i & 15) << 3;
    *(short8*)&Kb[row * LDW + c8] = *(const short8*)(base + (size_t)row * 3072 + 1024 + c8);
  }
  // stage V transposed
  for (int i = tid; i < 128 * 128; i += 256) {
    const int d = i & 127, key = i >> 7;
    Vt[d * LDW + key] = base[(size_t)key * 3072 + 2048 + d];
  }

  // Q fragments straight from global (rows wave*32 .. +32)
  short8 a[2][4];
  #pragma unroll
  for (int m = 0; m < 2; ++m) {
    const int row = wave * 32 + m * 16 + r;
    const u16* qp = base + (size_t)row * 3072;
    #pragma unroll
    for (int ks = 0; ks < 4; ++ks)
      a[m][ks] = *(const short8*)(qp + ks * 32 + kg * 8);
  }
  __syncthreads();

  // QK^T
  f32x4 acc[2][8];
  #pragma unroll
  for (int m = 0; m < 2; ++m)
    #pragma unroll
    for (int n = 0; n < 8; ++n) acc[m][n] = f32x4{0.f, 0.f, 0.f, 0.f};
  #pragma unroll
  for (int n = 0; n < 8; ++n) {
    #pragma unroll
    for (int ks = 0; ks < 4; ++ks) {
      short8 bf = *(const short8*)&Kb[(n * 16 + r) * LDW + ks * 32 + kg * 8];
      #pragma unroll
      for (int m = 0; m < 2; ++m)
        acc[m][n] = __builtin_amdgcn_mfma_f32_16x16x32_bf16(a[m][ks], bf, acc[m][n], 0, 0, 0);
    }
  }

  // row softmax (reduce over r across 16 lanes)
  const float sc = 0.08838834764831845f;  // 1/sqrt(128)
  #pragma unroll
  for (int m = 0; m < 2; ++m) {
    #pragma unroll
    for (int i = 0; i < 4; ++i) {
      float mx = -1e30f;
      #pragma unroll
      for (int n = 0; n < 8; ++n) mx = fmaxf(mx, acc[m][n][i]);
      #pragma unroll
      for (int msk = 1; msk < 16; msk <<= 1) mx = fmaxf(mx, __shfl_xor(mx, msk, 64));
      float s = 0.f;
      #pragma unroll
      for (int n = 0; n < 8; ++n) { float pv = __expf((acc[m][n][i] - mx) * sc); acc[m][n][i] = pv; s += pv; }
      #pragma unroll
      for (int msk = 1; msk < 16; msk <<= 1) s += __shfl_xor(s, msk, 64);
      const float inv = 1.f / s;
      #pragma unroll
      for (int n = 0; n < 8; ++n) {
        const int prow = wave * 32 + m * 16 + kg * 4 + i;
        Pb[prow * LDW + n * 16 + r] = f2bu(acc[m][n][i] * inv);
      }
    }
  }
  // Pb rows are wave-private: no barrier needed

  // PV
  f32x4 oacc[2][8];
  #pragma unroll
  for (int m = 0; m < 2; ++m)
    #pragma unroll
    for (int n = 0; n < 8; ++n) oacc[m][n] = f32x4{0.f, 0.f, 0.f, 0.f};
  #pragma unroll
  for (int ks = 0; ks < 4; ++ks) {
    short8 pa[2];
    #pragma unroll
    for (int m = 0; m < 2; ++m)
      pa[m] = *(const short8*)&Pb[(wave * 32 + m * 16 + r) * LDW + ks * 32 + kg * 8];
    #pragma unroll
    for (int n = 0; n < 8; ++n) {
      short8 vb = *(const short8*)&Vt[(n * 16 + r) * LDW + ks * 32 + kg * 8];
      #pragma unroll
      for (int m = 0; m < 2; ++m)
        oacc[m][n] = __builtin_amdgcn_mfma_f32_16x16x32_bf16(pa[m], vb, oacc[m][n], 0, 0, 0);
    }
  }

  u16* op = ATTb + ((size_t)b * 128) * 1024 + h * 128;
  #pragma unroll
  for (int m = 0; m < 2; ++m) {
    #pragma unroll
    for (int n = 0; n < 8; ++n) {
      #pragma unroll
      for (int i = 0; i < 4; ++i) {
        const int row = wave * 32 + m * 16 + kg * 4 + i;
        op[(size_t)row * 1024 + n * 16 + r] = f2bu(oacc[m][n][i]);
      }
    }
  }
}
#undef LDW

// ---------- router stage 1: logits + top-2 softmax -> choice/probs (NO atomics) ----------
__global__ __launch_bounds__(256) void router_kernel(const float* __restrict__ X, const float* __restrict__ rw,
    const float* __restrict__ rb, int* __restrict__ choice, float* __restrict__ prob2)
{
  const int token = blockIdx.x * 4 + (threadIdx.x >> 6);
  const int lane = threadIdx.x & 63;
  const float* xp = X + ((size_t)token << 10);
  float a0 = 0, a1 = 0, a2 = 0, a3 = 0;
  #pragma unroll
  for (int j = 0; j < 16; ++j) {
    const int k = lane + (j << 6);
    const float x = xp[k];
    const float4 w = *(const float4*)(rw + ((size_t)k << 2));
    a0 += x * w.x; a1 += x * w.y; a2 += x * w.z; a3 += x * w.w;
  }
  a0 = waveRedSum(a0); a1 = waveRedSum(a1); a2 = waveRedSum(a2); a3 = waveRedSum(a3);
  if (lane == 0) {
    float v[4] = {a0 + rb[0], a1 + rb[1], a2 + rb[2], a3 + rb[3]};
    int i1 = 0;
    for (int e = 1; e < 4; ++e) if (v[e] > v[i1]) i1 = e;       // earliest max (top_k tie rule)
    int i2 = (i1 == 0) ? 1 : 0;
    for (int e = 0; e < 4; ++e) if (e != i1 && v[e] > v[i2]) i2 = e;
    const float p2 = __expf(v[i2] - v[i1]);
    const float is = 1.f / (1.f + p2);
    choice[token] = i1 | (i2 << 8);
    prob2[token * 2]     = is;
    prob2[token * 2 + 1] = p2 * is;
  }
}

// ---------- router stage 2: 4 blocks (one per expert) build token-ascending compact lists ----------
__global__ __launch_bounds__(256) void build_lists_kernel(
    const int* __restrict__ choice, const float* __restrict__ prob2,
    int* __restrict__ cnt, int* __restrict__ tok, float* __restrict__ prob, int* __restrict__ slot)
{
  const int e = blockIdx.x;
  const int tid = threadIdx.x;
  __shared__ int sc[256];
  const int t0 = tid << 5;                      // 32 tokens per thread
  int mycount = 0;
  int code[32];                                  // 0=no, 1=top1, 2=top2
  #pragma unroll
  for (int j = 0; j < 32; ++j) {
    const int c = choice[t0 + j];
    const int m = ((c & 255) == e) ? 1 : (((c >> 8) == e) ? 2 : 0);
    code[j] = m;
    mycount += (m != 0);
  }
  sc[tid] = mycount;
  __syncthreads();
  for (int off = 1; off < 256; off <<= 1) {     // Hillis-Steele inclusive scan
    const int add = (tid >= off) ? sc[tid - off] : 0;
    __syncthreads();
    sc[tid] += add;
    __syncthreads();
  }
  int pos = e * 8192 + sc[tid] - mycount;        // exclusive offset
  #pragma unroll
  for (int j = 0; j < 32; ++j) {
    if (code[j]) {
      const int token = t0 + j;
      tok[pos] = token;
      prob[pos] = prob2[token * 2 + (code[j] - 1)];
      slot[pos] = code[j] - 1;
      ++pos;
    }
  }
  if (tid == 255) cnt[e] = sc[255];
}

// ---------- pooling score ----------
__global__ __launch_bounds__(256) void score_kernel(const float* __restrict__ X, const float* __restrict__ aw,
    const float* __restrict__ ab, float* __restrict__ S)
{
  const int token = blockIdx.x * 4 + (threadIdx.x >> 6);
  const int lane = threadIdx.x & 63;
  const float* xp = X + ((size_t)token << 10);
  float s = 0.f;
  #pragma unroll
  for (int j = 0; j < 16; ++j) { const int k = lane + (j << 6); s += xp[k] * aw[k]; }
  s = waveRedSum(s);
  if (lane == 0) S[token] = s + ab[0];
}

// ---------- softmax over S per batch + weighted pool ----------
__global__ __launch_bounds__(256) void pool_kernel(const float* __restrict__ X, const float* __restrict__ S,
                                                   float* __restrict__ P)
{
  const int b = blockIdx.x;
  const int tid = threadIdx.x;
  __shared__ float p[128];
  if (tid < 128) p[tid] = S[b * 128 + tid];
  __syncthreads();
  float mx = -1e30f;
  for (int t = 0; t < 128; ++t) mx = fmaxf(mx, p[t]);
  float sum = 0.f;
  for (int t = 0; t < 128; ++t) sum += __expf(p[t] - mx);
  const float inv = 1.f / sum;
  __syncthreads();
  if (tid < 128) p[tid] = __expf(p[tid] - mx) * inv;
  __syncthreads();
  float acc[4] = {0.f, 0.f, 0.f, 0.f};
  for (int t = 0; t < 128; ++t) {
    const float pt = p[t];
    const float* xp = X + ((size_t)(b * 128 + t) << 10) + tid;
    #pragma unroll
    for (int j = 0; j < 4; ++j) acc[j] += pt * xp[j << 8];
  }
  #pragma unroll
  for (int j = 0; j < 4; ++j) P[((size_t)b << 10) + tid + (j << 8)] = acc[j];
}

// ---------- task heads ----------
__global__ __launch_bounds__(256) void heads_kernel(const float* __restrict__ P, const float* __restrict__ hw,
    const float* __restrict__ hb, float* __restrict__ out)
{
  const int idx = blockIdx.x * 4 + (threadIdx.x >> 6);
  const int lane = threadIdx.x & 63;
  const int t = idx >> 8, b = (idx >> 2) & 63, c = idx & 3;
  const float* pp = P + ((size_t)b << 10);
  const float* wp = hw + (size_t)t * 4096 + c;
  float s = 0.f;
  #pragma unroll
  for (int j = 0; j < 16; ++j) { const int k = lane + (j << 6); s += pp[k] * wp[(size_t)k << 2]; }
  s = waveRedSum(s);
  if (lane == 0) out[idx] = s + hb[t * 4 + c];
}

// ---------- host ----------
extern "C" void kernel_launch(void* const* d_in, const int* in_sizes, int n_in,
                              void* d_out, int out_size, void* d_ws, size_t ws_size,
                              hipStream_t stream)
{
  (void)in_sizes; (void)n_in; (void)out_size; (void)ws_size;
  const float* vis        = (const float*)d_in[0];
  const float* proj_w     = (const float*)d_in[1];
  const float* proj_b     = (const float*)d_in[2];
  const float* in_proj_w  = (const float*)d_in[3];
  const float* in_proj_b  = (const float*)d_in[4];
  const float* out_proj_w = (const float*)d_in[5];
  const float* out_proj_b = (const float*)d_in[6];
  const float* ln1_g      = (const float*)d_in[7];
  const float* ln1_b      = (const float*)d_in[8];
  const float* ln2_g      = (const float*)d_in[9];
  const float* ln2_b      = (const float*)d_in[10];
  const float* router_w   = (const float*)d_in[11];
  const float* router_b   = (const float*)d_in[12];
  const float* ew1        = (const float*)d_in[13];
  const float* eb1        = (const float*)d_in[14];
  const float* ew2        = (const float*)d_in[15];
  const float* eb2        = (const float*)d_in[16];
  const float* attn_w     = (const float*)d_in[17];
  const float* attn_b     = (const float*)d_in[18];
  const float* heads_w    = (const float*)d_in[19];
  const float* heads_b    = (const float*)d_in[20];
  float* out = (float*)d_out;

  char* p = (char*)d_ws;
  auto take = [&](size_t bytes) -> char* {
    char* q = p; p += (bytes + 255) & ~(size_t)255; return q;
  };
  float* X    = (float*)take(8192ULL * 1024 * 4);
  u16*   Xb   = (u16*)  take(8192ULL * 1024 * 2);
  char*  QKVr = take(8192ULL * 3072 * 4);        // region: QKVb | O, MOE0, MOE1
  u16*   ATTb = (u16*)  take(8192ULL * 1024 * 2);
  u16*   H    = (u16*)  take(8192ULL * 2048 * 2);
  int*   CNT  = (int*)  take(4 * 4);
  int*   CHOICE = (int*)take(8192ULL * 4);
  float* PROB2  = (float*)take(8192ULL * 2 * 4);
  int*   TOK  = (int*)  take(4ULL * 8192 * 4);
  float* PROB = (float*)take(4ULL * 8192 * 4);
  int*   SLOT = (int*)  take(4ULL * 8192 * 4);
  float* S    = (float*)take(8192ULL * 4);
  float* POOL = (float*)take(64ULL * 1024 * 4);
  u16*   Wqkv = (u16*)  take(3072ULL * 1024 * 2);
  u16*   Wout = (u16*)  take(1024ULL * 1024 * 2);
  u16*   We1  = (u16*)  take(4ULL * 2048 * 1024 * 2);
  u16*   We2  = (u16*)  take(4ULL * 1024 * 2048 * 2);
  // aliases into QKV region (QKVb dead after attn; O dead after ln1)
  u16*   QKVb = (u16*)QKVr;                               // 50.3 MB
  float* O    = (float*)QKVr;                             // 33.5 MB
  float* MOE0 = (float*)(QKVr + 33554432);                // 33.5 MB
  float* MOE1 = (float*)(QKVr + 67108864);                // 33.5 MB
  u16*   Wproj = We1;                  // used before layer 0 overwrites We1
  u16*   VISb  = H;                    // vis bf16 (25.2MB <= 33.5MB)

  const dim3 tb(32, 8);

  // projection: X = vis @ proj_w + proj_b
  tconv_kernel<<<dim3(1024 / 32, 1536 / 32, 1), tb, 0, stream>>>(proj_w, Wproj, 1536, 1024);
  conv_kernel<<<(8192 * 1536 / 4) / 256, 256, 0, stream>>>(vis, VISb);
  gemm_bt<0><<<dim3(8, 64), 256, 0, stream>>>(VISb, Wproj, proj_b, X, nullptr, 1024, 1536);
  pe_kernel<<<8192 * 1024 / 256, 256, 0, stream>>>(X, Xb);

  for (int l = 0; l < 4; ++l) {
    tconv_kernel<<<dim3(3072 / 32, 1024 / 32, 1), tb, 0, stream>>>(in_proj_w + (size_t)l * 1024 * 3072, Wqkv, 1024, 3072);
    tconv_kernel<<<dim3(1024 / 32, 1024 / 32, 1), tb, 0, stream>>>(out_proj_w + (size_t)l * 1024 * 1024, Wout, 1024, 1024);
    tconv_kernel<<<dim3(2048 / 32, 1024 / 32, 4), tb, 0, stream>>>(ew1 + (size_t)l * 4 * 1024 * 2048, We1, 1024, 2048);
    tconv_kernel<<<dim3(1024 / 32, 2048 / 32, 4), tb, 0, stream>>>(ew2 + (size_t)l * 4 * 2048 * 1024, We2, 2048, 1024);

    gemm_bt<2><<<dim3(24, 64), 256, 0, stream>>>(Xb, Wqkv, in_proj_b + l * 3072, nullptr, QKVb, 3072, 1024);
    attn_mfma_kernel<<<512, 256, 0, stream>>>(QKVb, ATTb);
    gemm_bt<0><<<dim3(8, 64), 256, 0, stream>>>(ATTb, Wout, out_proj_b + l * 1024, O, nullptr, 1024, 1024);
    ln_kernel<<<8192, 256, 0, stream>>>(X, O, ln1_g + l * 1024, ln1_b + l * 1024, X, Xb);

    router_kernel<<<2048, 256, 0, stream>>>(X, router_w + l * 4096, router_b + l * 4, CHOICE, PROB2);
    build_lists_kernel<<<4, 256, 0, stream>>>(CHOICE, PROB2, CNT, TOK, PROB, SLOT);
    for (int e = 0; e < 4; ++e) {
      gemm_moe1<<<dim3(16, 64), 256, 0, stream>>>(Xb, We1 + (size_t)e * 2048 * 1024,
          eb1 + (size_t)(l * 4 + e) * 2048, H, TOK + e * 8192, CNT + e);
      gemm_moe2<<<dim3(8, 64), 256, 0, stream>>>(H, We2 + (size_t)e * 1024 * 2048,
          eb2 + (size_t)(l * 4 + e) * 1024, MOE0, MOE1,
          TOK + e * 8192, PROB + e * 8192, SLOT + e * 8192, CNT + e);
    }
    ln2_kernel<<<8192, 256, 0, stream>>>(X, MOE0, MOE1, ln2_g + l * 1024, ln2_b + l * 1024, X, Xb);
  }

  score_kernel<<<2048, 256, 0, stream>>>(X, attn_w, attn_b, S);
  pool_kernel<<<64, 256, 0, stream>>>(X, S, POOL);
  heads_kernel<<<256, 256, 0, stream>>>(POOL, heads_w, heads_b, out);
}